// Round 6
// baseline (269.174 us; speedup 1.0000x reference)
//
#include <hip/hip_runtime.h>
#include <hip/hip_bf16.h>

typedef __attribute__((ext_vector_type(8))) short bf16x8;
typedef __attribute__((ext_vector_type(4))) float f32x4;

struct bf16x8_s { __hip_bfloat16 h[8]; };
struct bf16x4_s { __hip_bfloat16 h[4]; };

// ---------------- fp32 -> bf16 conversion (8 elems/thread) ----------------
__global__ void cvt_kernel(const float* __restrict__ in,
                           __hip_bfloat16* __restrict__ out, int n8) {
  int i = blockIdx.x * blockDim.x + threadIdx.x;
  if (i >= n8) return;
  const float4* p = reinterpret_cast<const float4*>(in) + (size_t)i * 2;
  float4 a = p[0], b = p[1];
  bf16x8_s o;
  o.h[0] = __float2bfloat16(a.x); o.h[1] = __float2bfloat16(a.y);
  o.h[2] = __float2bfloat16(a.z); o.h[3] = __float2bfloat16(a.w);
  o.h[4] = __float2bfloat16(b.x); o.h[5] = __float2bfloat16(b.y);
  o.h[6] = __float2bfloat16(b.z); o.h[7] = __float2bfloat16(b.w);
  *reinterpret_cast<bf16x8_s*>(out + (size_t)i * 8) = o;
}

// all 4 weight matrices in one dispatch (dsts contiguous at wb)
__global__ void cvt4_kernel(const float* __restrict__ w0,
                            const float* __restrict__ w1,
                            const float* __restrict__ w2,
                            const float* __restrict__ w3,
                            __hip_bfloat16* __restrict__ out) {
  const int bid = blockIdx.x;
  const int seg = bid >> 9;
  const int i = (bid & 511) * 256 + threadIdx.x;  // < 131072 groups of 8
  const float* src = seg == 0 ? w0 : seg == 1 ? w1 : seg == 2 ? w2 : w3;
  const float4* p = reinterpret_cast<const float4*>(src) + (size_t)i * 2;
  float4 a = p[0], b = p[1];
  bf16x8_s o;
  o.h[0] = __float2bfloat16(a.x); o.h[1] = __float2bfloat16(a.y);
  o.h[2] = __float2bfloat16(a.z); o.h[3] = __float2bfloat16(a.w);
  o.h[4] = __float2bfloat16(b.x); o.h[5] = __float2bfloat16(b.y);
  o.h[6] = __float2bfloat16(b.z); o.h[7] = __float2bfloat16(b.w);
  *reinterpret_cast<bf16x8_s*>(out + (size_t)seg * 1048576 + (size_t)i * 8) = o;
}

// ---------------- fused QKV GEMM: [8192x1024] @ [3072x1024]^T --------------
// Column-block sel: 0 -> Q (scaled by 0.125*log2e), 1 -> K, 2 -> V-transpose.
__global__ __launch_bounds__(256) void gemm_qkv(
    const __hip_bfloat16* __restrict__ A, const __hip_bfloat16* __restrict__ W,
    const float* __restrict__ bq, const float* __restrict__ bk,
    const float* __restrict__ bv, __hip_bfloat16* __restrict__ Qs,
    __hip_bfloat16* __restrict__ Ks, __hip_bfloat16* __restrict__ Vts) {
  constexpr int K = 1024, BK = 64;
  __shared__ __hip_bfloat16 As[128][BK];
  __shared__ __hip_bfloat16 Ws[128][BK];
  const int tid = threadIdx.x;
  const int lane = tid & 63;
  const int lrow = lane & 15;
  const int lhi = lane >> 4;
  const int lk8 = lhi * 8;
  const int wid = tid >> 6;
  const int wm = wid >> 1, wn = wid & 1;
  const int row0 = blockIdx.x * 128;
  const int cb = blockIdx.y;            // 0..23
  const int sel = cb >> 3;              // 0:Q 1:K 2:V
  const int col0 = (cb & 7) * 128;      // local col within the [.][1024] out
  const int wr0 = cb * 128;             // global W row

  f32x4 acc[4][4] = {};

  for (int k0 = 0; k0 < K; k0 += BK) {
#pragma unroll
    for (int c = 0; c < 4; ++c) {
      const int e = (c * 256 + tid) * 8;
      const int eb = (c * 256 + (tid & 192)) * 8;
      const int r = e >> 6, cc = e & 63;
      __builtin_amdgcn_global_load_lds(
          (const __attribute__((address_space(1))) void*)(A + (size_t)(row0 + r) * K + k0 + cc),
          (__attribute__((address_space(3))) void*)(&As[0][0] + eb), 16, 0, 0);
    }
#pragma unroll
    for (int c = 0; c < 4; ++c) {
      const int e = (c * 256 + tid) * 8;
      const int eb = (c * 256 + (tid & 192)) * 8;
      const int r = e >> 6, cc = e & 63;
      __builtin_amdgcn_global_load_lds(
          (const __attribute__((address_space(1))) void*)(W + (size_t)(wr0 + r) * K + k0 + cc),
          (__attribute__((address_space(3))) void*)(&Ws[0][0] + eb), 16, 0, 0);
    }
    __syncthreads();
#pragma unroll
    for (int kk = 0; kk < 2; ++kk) {
      bf16x8 af[4], bfr[4];
#pragma unroll
      for (int m = 0; m < 4; ++m)
        af[m] = *reinterpret_cast<const bf16x8*>(&As[wm * 64 + m * 16 + lrow][kk * 32 + lk8]);
#pragma unroll
      for (int n = 0; n < 4; ++n)
        bfr[n] = *reinterpret_cast<const bf16x8*>(&Ws[wn * 64 + n * 16 + lrow][kk * 32 + lk8]);
#pragma unroll
      for (int m = 0; m < 4; ++m)
#pragma unroll
        for (int n = 0; n < 4; ++n)
          acc[m][n] = __builtin_amdgcn_mfma_f32_16x16x32_bf16(af[m], bfr[n], acc[m][n], 0, 0, 0);
    }
    __syncthreads();
  }

  const float* bias = sel == 0 ? bq : sel == 1 ? bk : bv;
  float bv4[4];
#pragma unroll
  for (int n = 0; n < 4; ++n) bv4[n] = bias[col0 + wn * 64 + n * 16 + lrow];

#pragma unroll
  for (int m = 0; m < 4; ++m)
#pragma unroll
    for (int n = 0; n < 4; ++n)
#pragma unroll
      for (int i = 0; i < 4; ++i) {
        const int row = row0 + wm * 64 + m * 16 + lhi * 4 + i;
        const int col = col0 + wn * 64 + n * 16 + lrow;
        const float v = acc[m][n][i] + bv4[n];
        if (sel == 0) {
          Qs[(size_t)row * 1024 + col] =
              __float2bfloat16(v * 0.18033688011112042f);
        } else if (sel == 1) {
          Ks[(size_t)row * 1024 + col] = __float2bfloat16(v);
        } else {
          const int t = row & 2047, bb = row >> 11;
          Vts[((size_t)((bb * 16 + (col >> 6)) * 64 + (col & 63))) * 2048 + t] =
              __float2bfloat16(v);
        }
      }
}

// ---------------- projection GEMM: fp32 out ---------------------------------
__global__ __launch_bounds__(256) void gemm_proj(
    const __hip_bfloat16* __restrict__ A, const __hip_bfloat16* __restrict__ W,
    const float* __restrict__ bias, float* __restrict__ Cout) {
  constexpr int K = 1024, N = 1024, BK = 64;
  __shared__ __hip_bfloat16 As[128][BK];
  __shared__ __hip_bfloat16 Ws[128][BK];
  const int tid = threadIdx.x;
  const int lane = tid & 63;
  const int lrow = lane & 15;
  const int lhi = lane >> 4;
  const int lk8 = lhi * 8;
  const int wid = tid >> 6;
  const int wm = wid >> 1, wn = wid & 1;
  const int row0 = blockIdx.x * 128, col0 = blockIdx.y * 128;

  f32x4 acc[4][4] = {};

  for (int k0 = 0; k0 < K; k0 += BK) {
#pragma unroll
    for (int c = 0; c < 4; ++c) {
      const int e = (c * 256 + tid) * 8;
      const int eb = (c * 256 + (tid & 192)) * 8;
      const int r = e >> 6, cc = e & 63;
      __builtin_amdgcn_global_load_lds(
          (const __attribute__((address_space(1))) void*)(A + (size_t)(row0 + r) * K + k0 + cc),
          (__attribute__((address_space(3))) void*)(&As[0][0] + eb), 16, 0, 0);
    }
#pragma unroll
    for (int c = 0; c < 4; ++c) {
      const int e = (c * 256 + tid) * 8;
      const int eb = (c * 256 + (tid & 192)) * 8;
      const int r = e >> 6, cc = e & 63;
      __builtin_amdgcn_global_load_lds(
          (const __attribute__((address_space(1))) void*)(W + (size_t)(col0 + r) * K + k0 + cc),
          (__attribute__((address_space(3))) void*)(&Ws[0][0] + eb), 16, 0, 0);
    }
    __syncthreads();
#pragma unroll
    for (int kk = 0; kk < 2; ++kk) {
      bf16x8 af[4], bfr[4];
#pragma unroll
      for (int m = 0; m < 4; ++m)
        af[m] = *reinterpret_cast<const bf16x8*>(&As[wm * 64 + m * 16 + lrow][kk * 32 + lk8]);
#pragma unroll
      for (int n = 0; n < 4; ++n)
        bfr[n] = *reinterpret_cast<const bf16x8*>(&Ws[wn * 64 + n * 16 + lrow][kk * 32 + lk8]);
#pragma unroll
      for (int m = 0; m < 4; ++m)
#pragma unroll
        for (int n = 0; n < 4; ++n)
          acc[m][n] = __builtin_amdgcn_mfma_f32_16x16x32_bf16(af[m], bfr[n], acc[m][n], 0, 0, 0);
    }
    __syncthreads();
  }

  float bv4[4];
#pragma unroll
  for (int n = 0; n < 4; ++n) bv4[n] = bias[col0 + wn * 64 + n * 16 + lrow];

#pragma unroll
  for (int m = 0; m < 4; ++m)
#pragma unroll
    for (int n = 0; n < 4; ++n)
#pragma unroll
      for (int i = 0; i < 4; ++i) {
        const int row = row0 + wm * 64 + m * 16 + lhi * 4 + i;
        const int col = col0 + wn * 64 + n * 16 + lrow;
        Cout[(size_t)row * N + col] = acc[m][n][i] + bv4[n];
      }
}

// ---------------- flash attention ------------------------------------------
// Block = 4 waves x 32 q-rows sharing double-buffered K/V LDS tiles
// (global_load_lds, linear dest + inverse-XOR-swizzled source; reads apply
// the same XOR). P routed through a 2KB/wave XOR-swizzled LDS buffer,
// j-halves sequentially (in-order DS keeps WAR safe). 40 KB LDS -> 4
// blocks/CU. Swapped QK^T, exp2 domain (Q pre-scaled), T13 defer-max, T5
// setprio.

__device__ __forceinline__ void stage_kv(char* __restrict__ smem, int buf,
                                         const __hip_bfloat16* __restrict__ Kb,
                                         const __hip_bfloat16* __restrict__ Vb,
                                         int kv0, int tid) {
  const int w = tid >> 6, l = tid & 63;
  char* base = smem + buf * 16384;
#pragma unroll
  for (int s = 0; s < 2; ++s) {
    const int c = s * 256 + w * 64 + l;
    const int row = c >> 3;
    const int scb = ((c & 7) << 4) ^ ((row & 7) << 4);
    __builtin_amdgcn_global_load_lds(
        (const __attribute__((address_space(1))) void*)(Kb + (size_t)(kv0 + row) * 1024 + (scb >> 1)),
        (__attribute__((address_space(3))) void*)(base + s * 4096 + w * 1024), 16, 0, 0);
  }
#pragma unroll
  for (int s = 0; s < 2; ++s) {
    const int c = s * 256 + w * 64 + l;
    const int row = c >> 3;
    const int scb = ((c & 7) << 4) ^ ((row & 7) << 4);
    __builtin_amdgcn_global_load_lds(
        (const __attribute__((address_space(1))) void*)(Vb + (size_t)row * 2048 + kv0 + (scb >> 1)),
        (__attribute__((address_space(3))) void*)(base + 8192 + s * 4096 + w * 1024), 16, 0, 0);
  }
}

template <bool MASKED>
__device__ __forceinline__ void attn_step(
    int kv0, int q0w, int lrow, int lhi, const char* __restrict__ kvb,
    const bf16x8 qf[2][2], f32x4 o[2][4], float m[2], float l[2],
    char* __restrict__ Pw) {
  constexpr float TH = 8.0f;
  const int xr = (lrow & 7) << 4;
  // ---- S^T = K @ Q^T from swizzled LDS (kf shared across both q-fragments)
  f32x4 s[2][4] = {};
  __builtin_amdgcn_s_setprio(1);
#pragma unroll
  for (int g = 0; g < 4; ++g) {
    const char* rowp = kvb + (g * 16 + lrow) * 128;
#pragma unroll
    for (int kk = 0; kk < 2; ++kk) {
      bf16x8 kf = *reinterpret_cast<const bf16x8*>(rowp + ((kk * 64 + lhi * 16) ^ xr));
#pragma unroll
      for (int j = 0; j < 2; ++j)
        s[j][g] = __builtin_amdgcn_mfma_f32_16x16x32_bf16(kf, qf[j][kk], s[j][g], 0, 0, 0);
    }
  }
  __builtin_amdgcn_s_setprio(0);
  // ---- optional mask + balanced-tree row max
  float mx[2];
#pragma unroll
  for (int j = 0; j < 2; ++j) {
    if (MASKED) {
#pragma unroll
      for (int g = 0; g < 4; ++g)
#pragma unroll
        for (int i = 0; i < 4; ++i) {
          const int k = kv0 + g * 16 + lhi * 4 + i;
          if (k > q0w + j * 16 + lrow) s[j][g][i] = -1e30f;
        }
    }
    float gm[4];
#pragma unroll
    for (int g = 0; g < 4; ++g)
      gm[g] = fmaxf(fmaxf(s[j][g][0], s[j][g][1]), fmaxf(s[j][g][2], s[j][g][3]));
    float t = fmaxf(fmaxf(gm[0], gm[1]), fmaxf(gm[2], gm[3]));
    t = fmaxf(t, __shfl_xor(t, 16));
    t = fmaxf(t, __shfl_xor(t, 32));
    mx[j] = t;
  }
  // ---- T13 defer-max
  const int need = (mx[0] > m[0] + TH) || (mx[1] > m[1] + TH);
  if (__any(need)) {
#pragma unroll
    for (int j = 0; j < 2; ++j) {
      const float nm = fmaxf(m[j], mx[j]);
      const float al = exp2f(m[j] - nm);
      m[j] = nm;
      l[j] *= al;
      float a4[4];
#pragma unroll
      for (int i = 0; i < 4; ++i) a4[i] = __shfl(al, 4 * lhi + i, 16);
#pragma unroll
      for (int f = 0; f < 4; ++f)
#pragma unroll
        for (int i = 0; i < 4; ++i) o[j][f][i] *= a4[i];
    }
  }
  // ---- P = exp2(s - m) -> swizzled LDS -> A-fragments (j sequential; WAR
  // safe: in-order DS, compiler cannot prove P writes/reads disjoint)
  bf16x8 pf[2][2];
#pragma unroll
  for (int j = 0; j < 2; ++j) {
    float gs[4];
#pragma unroll
    for (int g = 0; g < 4; ++g) {
      bf16x4_s t4;
      float p0 = exp2f(s[j][g][0] - m[j]);
      float p1 = exp2f(s[j][g][1] - m[j]);
      float p2 = exp2f(s[j][g][2] - m[j]);
      float p3 = exp2f(s[j][g][3] - m[j]);
      t4.h[0] = __float2bfloat16(p0); t4.h[1] = __float2bfloat16(p1);
      t4.h[2] = __float2bfloat16(p2); t4.h[3] = __float2bfloat16(p3);
      gs[g] = (p0 + p1) + (p2 + p3);
      *reinterpret_cast<bf16x4_s*>(Pw + lrow * 128 + ((g * 32 + lhi * 8) ^ xr)) = t4;
    }
    float sum = (gs[0] + gs[1]) + (gs[2] + gs[3]);
    sum += __shfl_xor(sum, 16);
    sum += __shfl_xor(sum, 32);
    l[j] += sum;
#pragma unroll
    for (int n = 0; n < 2; ++n)
      pf[j][n] = *reinterpret_cast<const bf16x8*>(
          Pw + lrow * 128 + ((n * 64 + lhi * 16) ^ xr));
  }
  // ---- O += P V from swizzled LDS
  __builtin_amdgcn_s_setprio(1);
#pragma unroll
  for (int n = 0; n < 2; ++n)
#pragma unroll
    for (int f = 0; f < 4; ++f) {
      bf16x8 vf = *reinterpret_cast<const bf16x8*>(
          kvb + 8192 + (f * 16 + lrow) * 128 + ((n * 64 + lhi * 16) ^ xr));
#pragma unroll
      for (int j = 0; j < 2; ++j)
        o[j][f] = __builtin_amdgcn_mfma_f32_16x16x32_bf16(pf[j][n], vf, o[j][f], 0, 0, 0);
    }
  __builtin_amdgcn_s_setprio(0);
}

__global__ __launch_bounds__(256, 4) void attn_fwd(
    const __hip_bfloat16* __restrict__ Q, const __hip_bfloat16* __restrict__ Km,
    const __hip_bfloat16* __restrict__ Vt, __hip_bfloat16* __restrict__ Y) {
  constexpr int T = 2048, C = 1024, D = 64;
  const int tid = threadIdx.x;
  const int wid = tid >> 6;
  const int lane = tid & 63;
  const int lrow = lane & 15;
  const int lhi = lane >> 4;
  // XCD (n&7) owns bh-group; qt zigzags on the fast index so each CU's 4
  // co-resident blocks get balanced causal work ({15,0,14,1}... sums ~equal).
  const int n = blockIdx.x;
  const int xcd = n & 7;
  const int w8 = n >> 3;
  const int u = w8 & 15;
  const int bh = xcd * 8 + (w8 >> 4);
  const int qt = (u & 1) ? (u >> 1) : (15 - (u >> 1));
  const int b = bh >> 4, h = bh & 15;
  const int q0w = qt * 128 + wid * 32;

  const __hip_bfloat16* Qb = Q + ((size_t)b * T) * C + h * D;
  const __hip_bfloat16* Kb = Km + ((size_t)b * T) * C + h * D;
  const __hip_bfloat16* Vb = Vt + (size_t)bh * D * T;

  // LDS: [2 buf][K 8KB | V 8KB] = 32 KB, then per-wave swizzled P 4 x 2 KB.
  __shared__ char smem[40960];
  char* Pw = smem + 32768 + wid * 2048;

  bf16x8 qf[2][2];
#pragma unroll
  for (int j = 0; j < 2; ++j)
#pragma unroll
    for (int kk = 0; kk < 2; ++kk)
      qf[j][kk] = *reinterpret_cast<const bf16x8*>(
          Qb + (size_t)(q0w + j * 16 + lrow) * C + kk * 32 + lhi * 8);

  f32x4 o[2][4] = {};
  float m[2] = {-1e30f, -1e30f}, l[2] = {0.f, 0.f};

  const int nt = 2 * qt + 2;        // KV tiles the block must stream
  const int ns = (q0w >> 6) + 1;    // steps this wave computes (last masked)

  stage_kv(smem, 0, Kb, Vb, 0, tid);
  for (int t = 0; t < nt; ++t) {
    __syncthreads();  // drains stage-for-t loads (vmcnt) + retires t-1 reads
    if (t + 1 < nt) stage_kv(smem, (t + 1) & 1, Kb, Vb, (t + 1) * 64, tid);
    if (t < ns) {
      const char* kvb = smem + (t & 1) * 16384;
      if (t == ns - 1)
        attn_step<true>(t * 64, q0w, lrow, lhi, kvb, qf, o, m, l, Pw);
      else
        attn_step<false>(t * 64, q0w, lrow, lhi, kvb, qf, o, m, l, Pw);
    }
  }

  // ---- normalize + store
#pragma unroll
  for (int j = 0; j < 2; ++j) {
    float l4[4];
#pragma unroll
    for (int i = 0; i < 4; ++i) l4[i] = __shfl(l[j], 4 * lhi + i, 16);
#pragma unroll
    for (int f = 0; f < 4; ++f)
#pragma unroll
      for (int i = 0; i < 4; ++i) {
        const int row = q0w + j * 16 + 4 * lhi + i;
        Y[((size_t)b * T + row) * C + h * D + f * 16 + lrow] =
            __float2bfloat16(o[j][f][i] / l4[i]);
      }
  }
}

// ---------------- host launch ----------------------------------------------
extern "C" void kernel_launch(void* const* d_in, const int* in_sizes, int n_in,
                              void* d_out, int out_size, void* d_ws,
                              size_t ws_size, hipStream_t stream) {
  const float* x = (const float*)d_in[0];
  const float* Wq = (const float*)d_in[1];
  const float* bq = (const float*)d_in[2];
  const float* Wk = (const float*)d_in[3];
  const float* bk = (const float*)d_in[4];
  const float* Wv = (const float*)d_in[5];
  const float* bv = (const float*)d_in[6];
  const float* Wp = (const float*)d_in[7];
  const float* bp = (const float*)d_in[8];
  float* out = (float*)d_out;

  __hip_bfloat16* ws = (__hip_bfloat16*)d_ws;
  __hip_bfloat16* xb = ws;                   // 8388608
  __hip_bfloat16* wqb = xb + 8388608;        // 4 x 1048576, contiguous
  __hip_bfloat16* wpb = wqb + 3 * 1048576;
  __hip_bfloat16* Qs = wqb + 4 * 1048576;    // 8388608
  __hip_bfloat16* Ks = Qs + 8388608;
  __hip_bfloat16* Vts = Ks + 8388608;        // V^T: [B*H*64][2048]
  __hip_bfloat16* Ys = Vts + 8388608;        // attn out [B*T][C]

  cvt_kernel<<<4096, 256, 0, stream>>>(x, xb, 1048576);
  cvt4_kernel<<<2048, 256, 0, stream>>>(Wq, Wk, Wv, Wp, wqb);

  gemm_qkv<<<dim3(64, 24), 256, 0, stream>>>(xb, wqb, bq, bk, bv, Qs, Ks, Vts);

  attn_fwd<<<dim3(1024), 256, 0, stream>>>(Qs, Ks, Vts, Ys);

  gemm_proj<<<dim3(64, 8), 256, 0, stream>>>(Ys, wpb, bp, out);
}

// Round 7
// 216.779 us; speedup vs baseline: 1.2417x; 1.2417x over previous
//
#include <hip/hip_runtime.h>
#include <hip/hip_bf16.h>

typedef __attribute__((ext_vector_type(8))) short bf16x8;
typedef __attribute__((ext_vector_type(4))) float f32x4;

struct bf16x8_s { __hip_bfloat16 h[8]; };
struct bf16x4_s { __hip_bfloat16 h[4]; };

// ---------------- fp32 -> bf16 conversion (8 elems/thread) ----------------
__global__ void cvt_kernel(const float* __restrict__ in,
                           __hip_bfloat16* __restrict__ out, int n8) {
  int i = blockIdx.x * blockDim.x + threadIdx.x;
  if (i >= n8) return;
  const float4* p = reinterpret_cast<const float4*>(in) + (size_t)i * 2;
  float4 a = p[0], b = p[1];
  bf16x8_s o;
  o.h[0] = __float2bfloat16(a.x); o.h[1] = __float2bfloat16(a.y);
  o.h[2] = __float2bfloat16(a.z); o.h[3] = __float2bfloat16(a.w);
  o.h[4] = __float2bfloat16(b.x); o.h[5] = __float2bfloat16(b.y);
  o.h[6] = __float2bfloat16(b.z); o.h[7] = __float2bfloat16(b.w);
  *reinterpret_cast<bf16x8_s*>(out + (size_t)i * 8) = o;
}

// all 4 weight matrices in one dispatch (dsts contiguous at wb)
__global__ void cvt4_kernel(const float* __restrict__ w0,
                            const float* __restrict__ w1,
                            const float* __restrict__ w2,
                            const float* __restrict__ w3,
                            __hip_bfloat16* __restrict__ out) {
  const int bid = blockIdx.x;
  const int seg = bid >> 9;
  const int i = (bid & 511) * 256 + threadIdx.x;  // < 131072 groups of 8
  const float* src = seg == 0 ? w0 : seg == 1 ? w1 : seg == 2 ? w2 : w3;
  const float4* p = reinterpret_cast<const float4*>(src) + (size_t)i * 2;
  float4 a = p[0], b = p[1];
  bf16x8_s o;
  o.h[0] = __float2bfloat16(a.x); o.h[1] = __float2bfloat16(a.y);
  o.h[2] = __float2bfloat16(a.z); o.h[3] = __float2bfloat16(a.w);
  o.h[4] = __float2bfloat16(b.x); o.h[5] = __float2bfloat16(b.y);
  o.h[6] = __float2bfloat16(b.z); o.h[7] = __float2bfloat16(b.w);
  *reinterpret_cast<bf16x8_s*>(out + (size_t)seg * 1048576 + (size_t)i * 8) = o;
}

// ---------------- fused QKV GEMM: [8192x1024] @ [3072x1024]^T --------------
// Column-block sel: 0 -> Q (scaled by 0.125*log2e), 1 -> K, 2 -> V-transpose.
__global__ __launch_bounds__(256) void gemm_qkv(
    const __hip_bfloat16* __restrict__ A, const __hip_bfloat16* __restrict__ W,
    const float* __restrict__ bq, const float* __restrict__ bk,
    const float* __restrict__ bv, __hip_bfloat16* __restrict__ Qs,
    __hip_bfloat16* __restrict__ Ks, __hip_bfloat16* __restrict__ Vts) {
  constexpr int K = 1024, BK = 64;
  __shared__ __hip_bfloat16 As[128][BK];
  __shared__ __hip_bfloat16 Ws[128][BK];
  const int tid = threadIdx.x;
  const int lane = tid & 63;
  const int lrow = lane & 15;
  const int lhi = lane >> 4;
  const int lk8 = lhi * 8;
  const int wid = tid >> 6;
  const int wm = wid >> 1, wn = wid & 1;
  const int row0 = blockIdx.x * 128;
  const int cb = blockIdx.y;            // 0..23
  const int sel = cb >> 3;              // 0:Q 1:K 2:V
  const int col0 = (cb & 7) * 128;      // local col within the [.][1024] out
  const int wr0 = cb * 128;             // global W row

  f32x4 acc[4][4] = {};

  for (int k0 = 0; k0 < K; k0 += BK) {
#pragma unroll
    for (int c = 0; c < 4; ++c) {
      const int e = (c * 256 + tid) * 8;
      const int eb = (c * 256 + (tid & 192)) * 8;
      const int r = e >> 6, cc = e & 63;
      __builtin_amdgcn_global_load_lds(
          (const __attribute__((address_space(1))) void*)(A + (size_t)(row0 + r) * K + k0 + cc),
          (__attribute__((address_space(3))) void*)(&As[0][0] + eb), 16, 0, 0);
    }
#pragma unroll
    for (int c = 0; c < 4; ++c) {
      const int e = (c * 256 + tid) * 8;
      const int eb = (c * 256 + (tid & 192)) * 8;
      const int r = e >> 6, cc = e & 63;
      __builtin_amdgcn_global_load_lds(
          (const __attribute__((address_space(1))) void*)(W + (size_t)(wr0 + r) * K + k0 + cc),
          (__attribute__((address_space(3))) void*)(&Ws[0][0] + eb), 16, 0, 0);
    }
    __syncthreads();
#pragma unroll
    for (int kk = 0; kk < 2; ++kk) {
      bf16x8 af[4], bfr[4];
#pragma unroll
      for (int m = 0; m < 4; ++m)
        af[m] = *reinterpret_cast<const bf16x8*>(&As[wm * 64 + m * 16 + lrow][kk * 32 + lk8]);
#pragma unroll
      for (int n = 0; n < 4; ++n)
        bfr[n] = *reinterpret_cast<const bf16x8*>(&Ws[wn * 64 + n * 16 + lrow][kk * 32 + lk8]);
#pragma unroll
      for (int m = 0; m < 4; ++m)
#pragma unroll
        for (int n = 0; n < 4; ++n)
          acc[m][n] = __builtin_amdgcn_mfma_f32_16x16x32_bf16(af[m], bfr[n], acc[m][n], 0, 0, 0);
    }
    __syncthreads();
  }

  const float* bias = sel == 0 ? bq : sel == 1 ? bk : bv;
  float bv4[4];
#pragma unroll
  for (int n = 0; n < 4; ++n) bv4[n] = bias[col0 + wn * 64 + n * 16 + lrow];

#pragma unroll
  for (int m = 0; m < 4; ++m)
#pragma unroll
    for (int n = 0; n < 4; ++n)
#pragma unroll
      for (int i = 0; i < 4; ++i) {
        const int row = row0 + wm * 64 + m * 16 + lhi * 4 + i;
        const int col = col0 + wn * 64 + n * 16 + lrow;
        const float v = acc[m][n][i] + bv4[n];
        if (sel == 0) {
          Qs[(size_t)row * 1024 + col] =
              __float2bfloat16(v * 0.18033688011112042f);
        } else if (sel == 1) {
          Ks[(size_t)row * 1024 + col] = __float2bfloat16(v);
        } else {
          const int t = row & 2047, bb = row >> 11;
          Vts[((size_t)((bb * 16 + (col >> 6)) * 64 + (col & 63))) * 2048 + t] =
              __float2bfloat16(v);
        }
      }
}

// ---------------- projection GEMM: fp32 out ---------------------------------
__global__ __launch_bounds__(256) void gemm_proj(
    const __hip_bfloat16* __restrict__ A, const __hip_bfloat16* __restrict__ W,
    const float* __restrict__ bias, float* __restrict__ Cout) {
  constexpr int K = 1024, N = 1024, BK = 64;
  __shared__ __hip_bfloat16 As[128][BK];
  __shared__ __hip_bfloat16 Ws[128][BK];
  const int tid = threadIdx.x;
  const int lane = tid & 63;
  const int lrow = lane & 15;
  const int lhi = lane >> 4;
  const int lk8 = lhi * 8;
  const int wid = tid >> 6;
  const int wm = wid >> 1, wn = wid & 1;
  const int row0 = blockIdx.x * 128, col0 = blockIdx.y * 128;

  f32x4 acc[4][4] = {};

  for (int k0 = 0; k0 < K; k0 += BK) {
#pragma unroll
    for (int c = 0; c < 4; ++c) {
      const int e = (c * 256 + tid) * 8;
      const int eb = (c * 256 + (tid & 192)) * 8;
      const int r = e >> 6, cc = e & 63;
      __builtin_amdgcn_global_load_lds(
          (const __attribute__((address_space(1))) void*)(A + (size_t)(row0 + r) * K + k0 + cc),
          (__attribute__((address_space(3))) void*)(&As[0][0] + eb), 16, 0, 0);
    }
#pragma unroll
    for (int c = 0; c < 4; ++c) {
      const int e = (c * 256 + tid) * 8;
      const int eb = (c * 256 + (tid & 192)) * 8;
      const int r = e >> 6, cc = e & 63;
      __builtin_amdgcn_global_load_lds(
          (const __attribute__((address_space(1))) void*)(W + (size_t)(col0 + r) * K + k0 + cc),
          (__attribute__((address_space(3))) void*)(&Ws[0][0] + eb), 16, 0, 0);
    }
    __syncthreads();
#pragma unroll
    for (int kk = 0; kk < 2; ++kk) {
      bf16x8 af[4], bfr[4];
#pragma unroll
      for (int m = 0; m < 4; ++m)
        af[m] = *reinterpret_cast<const bf16x8*>(&As[wm * 64 + m * 16 + lrow][kk * 32 + lk8]);
#pragma unroll
      for (int n = 0; n < 4; ++n)
        bfr[n] = *reinterpret_cast<const bf16x8*>(&Ws[wn * 64 + n * 16 + lrow][kk * 32 + lk8]);
#pragma unroll
      for (int m = 0; m < 4; ++m)
#pragma unroll
        for (int n = 0; n < 4; ++n)
          acc[m][n] = __builtin_amdgcn_mfma_f32_16x16x32_bf16(af[m], bfr[n], acc[m][n], 0, 0, 0);
    }
    __syncthreads();
  }

  float bv4[4];
#pragma unroll
  for (int n = 0; n < 4; ++n) bv4[n] = bias[col0 + wn * 64 + n * 16 + lrow];

#pragma unroll
  for (int m = 0; m < 4; ++m)
#pragma unroll
    for (int n = 0; n < 4; ++n)
#pragma unroll
      for (int i = 0; i < 4; ++i) {
        const int row = row0 + wm * 64 + m * 16 + lhi * 4 + i;
        const int col = col0 + wn * 64 + n * 16 + lrow;
        Cout[(size_t)row * N + col] = acc[m][n][i] + bv4[n];
      }
}

// ---------------- flash attention ------------------------------------------
// Block = 4 waves x 32 q-rows sharing double-buffered K/V LDS tiles
// (global_load_lds, linear dest + inverse-XOR-swizzled source; reads apply
// the same XOR). P: per-wave private [2][16][72] bf16 (R4 form -- no reuse
// serialization). 51.2 KB LDS -> 3 blocks/CU. Swapped QK^T, exp2 domain
// (Q pre-scaled in GEMM), T13 defer-max, T5 setprio.

__device__ __forceinline__ void stage_kv(char* __restrict__ smem, int buf,
                                         const __hip_bfloat16* __restrict__ Kb,
                                         const __hip_bfloat16* __restrict__ Vb,
                                         int kv0, int tid) {
  const int w = tid >> 6, l = tid & 63;
  char* base = smem + buf * 16384;
#pragma unroll
  for (int s = 0; s < 2; ++s) {
    const int c = s * 256 + w * 64 + l;
    const int row = c >> 3;
    const int scb = ((c & 7) << 4) ^ ((row & 7) << 4);
    __builtin_amdgcn_global_load_lds(
        (const __attribute__((address_space(1))) void*)(Kb + (size_t)(kv0 + row) * 1024 + (scb >> 1)),
        (__attribute__((address_space(3))) void*)(base + s * 4096 + w * 1024), 16, 0, 0);
  }
#pragma unroll
  for (int s = 0; s < 2; ++s) {
    const int c = s * 256 + w * 64 + l;
    const int row = c >> 3;
    const int scb = ((c & 7) << 4) ^ ((row & 7) << 4);
    __builtin_amdgcn_global_load_lds(
        (const __attribute__((address_space(1))) void*)(Vb + (size_t)row * 2048 + kv0 + (scb >> 1)),
        (__attribute__((address_space(3))) void*)(base + 8192 + s * 4096 + w * 1024), 16, 0, 0);
  }
}

template <bool MASKED>
__device__ __forceinline__ void attn_step(
    int kv0, int q0w, int lrow, int lhi, const char* __restrict__ kvb,
    const bf16x8 qf[2][2], f32x4 o[2][4], float m[2], float l[2],
    __hip_bfloat16* __restrict__ P) {
  constexpr float TH = 8.0f;
  const int xr = (lrow & 7) << 4;
  // ---- S^T = K @ Q^T from swizzled LDS (kf shared across both q-fragments)
  f32x4 s[2][4] = {};
  __builtin_amdgcn_s_setprio(1);
#pragma unroll
  for (int g = 0; g < 4; ++g) {
    const char* rowp = kvb + (g * 16 + lrow) * 128;
#pragma unroll
    for (int kk = 0; kk < 2; ++kk) {
      bf16x8 kf = *reinterpret_cast<const bf16x8*>(rowp + ((kk * 64 + lhi * 16) ^ xr));
#pragma unroll
      for (int j = 0; j < 2; ++j)
        s[j][g] = __builtin_amdgcn_mfma_f32_16x16x32_bf16(kf, qf[j][kk], s[j][g], 0, 0, 0);
    }
  }
  __builtin_amdgcn_s_setprio(0);
  // ---- optional mask + balanced-tree row max
  float mx[2];
#pragma unroll
  for (int j = 0; j < 2; ++j) {
    if (MASKED) {
#pragma unroll
      for (int g = 0; g < 4; ++g)
#pragma unroll
        for (int i = 0; i < 4; ++i) {
          const int k = kv0 + g * 16 + lhi * 4 + i;
          if (k > q0w + j * 16 + lrow) s[j][g][i] = -1e30f;
        }
    }
    float gm[4];
#pragma unroll
    for (int g = 0; g < 4; ++g)
      gm[g] = fmaxf(fmaxf(s[j][g][0], s[j][g][1]), fmaxf(s[j][g][2], s[j][g][3]));
    float t = fmaxf(fmaxf(gm[0], gm[1]), fmaxf(gm[2], gm[3]));
    t = fmaxf(t, __shfl_xor(t, 16));
    t = fmaxf(t, __shfl_xor(t, 32));
    mx[j] = t;
  }
  // ---- T13 defer-max
  const int need = (mx[0] > m[0] + TH) || (mx[1] > m[1] + TH);
  if (__any(need)) {
#pragma unroll
    for (int j = 0; j < 2; ++j) {
      const float nm = fmaxf(m[j], mx[j]);
      const float al = exp2f(m[j] - nm);
      m[j] = nm;
      l[j] *= al;
      float a4[4];
#pragma unroll
      for (int i = 0; i < 4; ++i) a4[i] = __shfl(al, 4 * lhi + i, 16);
#pragma unroll
      for (int f = 0; f < 4; ++f)
#pragma unroll
        for (int i = 0; i < 4; ++i) o[j][f][i] *= a4[i];
    }
  }
  // ---- P = exp2(s - m), tree row-sum, P[q][k] -> per-wave LDS (stride 72)
#pragma unroll
  for (int j = 0; j < 2; ++j) {
    float gs[4];
#pragma unroll
    for (int g = 0; g < 4; ++g) {
      bf16x4_s t4;
      float p0 = exp2f(s[j][g][0] - m[j]);
      float p1 = exp2f(s[j][g][1] - m[j]);
      float p2 = exp2f(s[j][g][2] - m[j]);
      float p3 = exp2f(s[j][g][3] - m[j]);
      t4.h[0] = __float2bfloat16(p0); t4.h[1] = __float2bfloat16(p1);
      t4.h[2] = __float2bfloat16(p2); t4.h[3] = __float2bfloat16(p3);
      gs[g] = (p0 + p1) + (p2 + p3);
      *reinterpret_cast<bf16x4_s*>(P + (j * 16 + lrow) * 72 + g * 16 + lhi * 4) = t4;
    }
    float sum = (gs[0] + gs[1]) + (gs[2] + gs[3]);
    sum += __shfl_xor(sum, 16);
    sum += __shfl_xor(sum, 32);
    l[j] += sum;
  }
  // ---- read P as A-fragments, O += P V from swizzled LDS
  bf16x8 pf[2][2];
#pragma unroll
  for (int j = 0; j < 2; ++j)
#pragma unroll
    for (int n = 0; n < 2; ++n)
      pf[j][n] = *reinterpret_cast<const bf16x8*>(P + (j * 16 + lrow) * 72 + n * 32 + lhi * 8);
  __builtin_amdgcn_s_setprio(1);
#pragma unroll
  for (int n = 0; n < 2; ++n)
#pragma unroll
    for (int f = 0; f < 4; ++f) {
      bf16x8 vf = *reinterpret_cast<const bf16x8*>(
          kvb + 8192 + (f * 16 + lrow) * 128 + ((n * 64 + lhi * 16) ^ xr));
#pragma unroll
      for (int j = 0; j < 2; ++j)
        o[j][f] = __builtin_amdgcn_mfma_f32_16x16x32_bf16(pf[j][n], vf, o[j][f], 0, 0, 0);
    }
  __builtin_amdgcn_s_setprio(0);
}

__global__ __launch_bounds__(256, 3) void attn_fwd(
    const __hip_bfloat16* __restrict__ Q, const __hip_bfloat16* __restrict__ Km,
    const __hip_bfloat16* __restrict__ Vt, __hip_bfloat16* __restrict__ Y) {
  constexpr int T = 2048, C = 1024, D = 64;
  const int tid = threadIdx.x;
  const int wid = tid >> 6;
  const int lane = tid & 63;
  const int lrow = lane & 15;
  const int lhi = lane >> 4;
  // Block map (measured model: XCD = n&7; blocks n, n+256 share a CU).
  // j2 = co-residency round, s = CU slot group. qt chosen so each CU's 4
  // blocks have qt = {15-s, 8+s, 7-(s^1), s^1}: exactly 68 KV-tiles per CU,
  // heavy block first, lightest queued. Same bh for all 4 (K/V L2 reuse).
  const int n = blockIdx.x;
  const int xcd = n & 7;
  const int w8 = n >> 3;
  const int j2 = w8 >> 5;
  const int r = w8 & 31;
  const int s5 = r >> 3;
  const int bh = xcd * 8 + (r & 7);
  int p;
  if (j2 == 0) p = s5;
  else if (j2 == 1) p = 3 - s5;
  else if (j2 == 2) p = s5 ^ 1;
  else p = 3 - (s5 ^ 1);
  const int qt = 15 - (j2 * 4 + p);
  const int b = bh >> 4, h = bh & 15;
  const int q0w = qt * 128 + wid * 32;

  const __hip_bfloat16* Qb = Q + ((size_t)b * T) * C + h * D;
  const __hip_bfloat16* Kb = Km + ((size_t)b * T) * C + h * D;
  const __hip_bfloat16* Vb = Vt + (size_t)bh * D * T;

  // LDS: [2 buf][K 8KB | V 8KB] = 32 KB, then per-wave P (stride-72) 4x4608 B.
  __shared__ char smem[51200];
  __hip_bfloat16* P = (__hip_bfloat16*)(smem + 32768 + wid * 4608);

  bf16x8 qf[2][2];
#pragma unroll
  for (int j = 0; j < 2; ++j)
#pragma unroll
    for (int kk = 0; kk < 2; ++kk)
      qf[j][kk] = *reinterpret_cast<const bf16x8*>(
          Qb + (size_t)(q0w + j * 16 + lrow) * C + kk * 32 + lhi * 8);

  f32x4 o[2][4] = {};
  float m[2] = {-1e30f, -1e30f}, l[2] = {0.f, 0.f};

  const int nt = 2 * qt + 2;        // KV tiles the block must stream
  const int ns = (q0w >> 6) + 1;    // steps this wave computes (last masked)

  stage_kv(smem, 0, Kb, Vb, 0, tid);
  for (int t = 0; t < nt; ++t) {
    __syncthreads();  // drains stage-for-t loads (vmcnt) + retires t-1 reads
    if (t + 1 < nt) stage_kv(smem, (t + 1) & 1, Kb, Vb, (t + 1) * 64, tid);
    if (t < ns) {
      const char* kvb = smem + (t & 1) * 16384;
      if (t == ns - 1)
        attn_step<true>(t * 64, q0w, lrow, lhi, kvb, qf, o, m, l, P);
      else
        attn_step<false>(t * 64, q0w, lrow, lhi, kvb, qf, o, m, l, P);
    }
  }

  // ---- normalize + store
#pragma unroll
  for (int j = 0; j < 2; ++j) {
    float l4[4];
#pragma unroll
    for (int i = 0; i < 4; ++i) l4[i] = __shfl(l[j], 4 * lhi + i, 16);
#pragma unroll
    for (int f = 0; f < 4; ++f)
#pragma unroll
      for (int i = 0; i < 4; ++i) {
        const int row = q0w + j * 16 + 4 * lhi + i;
        Y[((size_t)b * T + row) * C + h * D + f * 16 + lrow] =
            __float2bfloat16(o[j][f][i] / l4[i]);
      }
  }
}

// ---------------- host launch ----------------------------------------------
extern "C" void kernel_launch(void* const* d_in, const int* in_sizes, int n_in,
                              void* d_out, int out_size, void* d_ws,
                              size_t ws_size, hipStream_t stream) {
  const float* x = (const float*)d_in[0];
  const float* Wq = (const float*)d_in[1];
  const float* bq = (const float*)d_in[2];
  const float* Wk = (const float*)d_in[3];
  const float* bk = (const float*)d_in[4];
  const float* Wv = (const float*)d_in[5];
  const float* bv = (const float*)d_in[6];
  const float* Wp = (const float*)d_in[7];
  const float* bp = (const float*)d_in[8];
  float* out = (float*)d_out;

  __hip_bfloat16* ws = (__hip_bfloat16*)d_ws;
  __hip_bfloat16* xb = ws;                   // 8388608
  __hip_bfloat16* wqb = xb + 8388608;        // 4 x 1048576, contiguous
  __hip_bfloat16* wpb = wqb + 3 * 1048576;
  __hip_bfloat16* Qs = wqb + 4 * 1048576;    // 8388608
  __hip_bfloat16* Ks = Qs + 8388608;
  __hip_bfloat16* Vts = Ks + 8388608;        // V^T: [B*H*64][2048]
  __hip_bfloat16* Ys = Vts + 8388608;        // attn out [B*T][C]

  cvt_kernel<<<4096, 256, 0, stream>>>(x, xb, 1048576);
  cvt4_kernel<<<2048, 256, 0, stream>>>(Wq, Wk, Wv, Wp, wqb);

  gemm_qkv<<<dim3(64, 24), 256, 0, stream>>>(xb, wqb, bq, bk, bv, Qs, Ks, Vts);

  attn_fwd<<<dim3(1024), 256, 0, stream>>>(Qs, Ks, Vts, Ys);

  gemm_proj<<<dim3(64, 8), 256, 0, stream>>>(Ys, wpb, bp, out);
}

// Round 8
// 201.730 us; speedup vs baseline: 1.3343x; 1.0746x over previous
//
#include <hip/hip_runtime.h>
#include <hip/hip_bf16.h>

typedef __attribute__((ext_vector_type(8))) short bf16x8;
typedef __attribute__((ext_vector_type(4))) float f32x4;

struct bf16x8_s { __hip_bfloat16 h[8]; };
struct bf16x4_s { __hip_bfloat16 h[4]; };

// ---------------- fp32 -> bf16 conversion (8 elems/thread) ----------------
__global__ void cvt_kernel(const float* __restrict__ in,
                           __hip_bfloat16* __restrict__ out, int n8) {
  int i = blockIdx.x * blockDim.x + threadIdx.x;
  if (i >= n8) return;
  const float4* p = reinterpret_cast<const float4*>(in) + (size_t)i * 2;
  float4 a = p[0], b = p[1];
  bf16x8_s o;
  o.h[0] = __float2bfloat16(a.x); o.h[1] = __float2bfloat16(a.y);
  o.h[2] = __float2bfloat16(a.z); o.h[3] = __float2bfloat16(a.w);
  o.h[4] = __float2bfloat16(b.x); o.h[5] = __float2bfloat16(b.y);
  o.h[6] = __float2bfloat16(b.z); o.h[7] = __float2bfloat16(b.w);
  *reinterpret_cast<bf16x8_s*>(out + (size_t)i * 8) = o;
}

__global__ void cvt4_kernel(const float* __restrict__ w0,
                            const float* __restrict__ w1,
                            const float* __restrict__ w2,
                            const float* __restrict__ w3,
                            __hip_bfloat16* __restrict__ out) {
  const int bid = blockIdx.x;
  const int seg = bid >> 9;
  const int i = (bid & 511) * 256 + threadIdx.x;
  const float* src = seg == 0 ? w0 : seg == 1 ? w1 : seg == 2 ? w2 : w3;
  const float4* p = reinterpret_cast<const float4*>(src) + (size_t)i * 2;
  float4 a = p[0], b = p[1];
  bf16x8_s o;
  o.h[0] = __float2bfloat16(a.x); o.h[1] = __float2bfloat16(a.y);
  o.h[2] = __float2bfloat16(a.z); o.h[3] = __float2bfloat16(a.w);
  o.h[4] = __float2bfloat16(b.x); o.h[5] = __float2bfloat16(b.y);
  o.h[6] = __float2bfloat16(b.z); o.h[7] = __float2bfloat16(b.w);
  *reinterpret_cast<bf16x8_s*>(out + (size_t)seg * 1048576 + (size_t)i * 8) = o;
}

// ---------------- 256x256 counted-vmcnt GEMM (K=1024, B^T weights) ---------
// 512 thr = 8 waves (2M x 4N); per-wave out 128x64; acc[8][4]; BK=64.
// LDS 128KB: A[2buf][256][64] @0, B[2buf][256][64] @65536, XOR-swizzled
// (byte ^= (row&7)<<4, involution: inverse-swizzled global source + swizzled
// ds_read). Per K-step: ph0{vmcnt(4);bar;read A0,B0;stage A0';mfma q00}
// ph1{vmcnt(2);bar;read B1;stage B0';mfma q01} ph2{read A1;stage A1';q10}
// ph3{stage B1';q11}. Stage order A0,B0,A1,B1 makes vmcnt(4)/(2) cover
// exactly the half-tiles each phase reads; loads stay in flight across
// barriers (raw s_barrier -- NOT __syncthreads, which drains vmcnt).
__device__ __forceinline__ void stage_half(const __hip_bfloat16* src,
                                           char* ldsbase, int tid) {
#pragma unroll
  for (int s = 0; s < 2; ++s) {
    const int c = s * 512 + tid;
    const int row = c >> 3;
    const int cb = ((c & 7) << 4) ^ ((row & 7) << 4);
    __builtin_amdgcn_global_load_lds(
        (const __attribute__((address_space(1))) void*)(src + (size_t)row * 1024 + (cb >> 1)),
        (__attribute__((address_space(3))) void*)(ldsbase + s * 8192 + (tid & 448) * 16),
        16, 0, 0);
  }
}

// MODE 0: fused QKV epilogue (Q scaled, K plain, V transposed), NTN=12.
// MODE 1: projection, fp32 out + bias, NTN=4.
template <int MODE>
__global__ __launch_bounds__(512, 2) void gemm256(
    const __hip_bfloat16* __restrict__ A, const __hip_bfloat16* __restrict__ W,
    const float* __restrict__ b0, const float* __restrict__ b1,
    const float* __restrict__ b2, void* __restrict__ O0,
    void* __restrict__ O1, void* __restrict__ O2, int NTN, int NB8) {
  constexpr int NT = 16;  // K=1024 / BK=64
  __shared__ char smem[131072];
  const int tid = threadIdx.x;
  const int lane = tid & 63;
  const int lrow = lane & 15;
  const int lhi = lane >> 4;
  const int wid = tid >> 6;
  const int wm = wid >> 2;   // 0..1
  const int wn = wid & 3;    // 0..3
  const int xr = (lrow & 7) << 4;

  const int n = blockIdx.x;
  const int wg = (n & 7) * NB8 + (n >> 3);  // bijective XCD swizzle (NB%8==0)
  const int tm = wg / NTN, tn = wg % NTN;

  const __hip_bfloat16* Ap = A + (size_t)tm * 256 * 1024;
  const __hip_bfloat16* Wp = W + (size_t)tn * 256 * 1024;

  f32x4 acc[8][4] = {};
  bf16x8 af[4][2], bf[2][2][2];

  // prologue: stage K-step 0 in order A0,B0,A1,B1 (matches vmcnt counting)
  stage_half(Ap, smem, tid);
  stage_half(Wp, smem + 65536, tid);
  stage_half(Ap + 128 * 1024, smem + 16384, tid);
  stage_half(Wp + 128 * 1024, smem + 65536 + 16384, tid);

  for (int t = 0; t < NT; ++t) {
    const char* Ab = smem + (t & 1) * 32768;
    const char* Bb = smem + 65536 + (t & 1) * 32768;
    char* An = smem + ((t + 1) & 1) * 32768;
    char* Bn = smem + 65536 + ((t + 1) & 1) * 32768;
    const __hip_bfloat16* As2 = Ap + (t + 1) * 64;
    const __hip_bfloat16* Ws2 = Wp + (t + 1) * 64;
    const bool st = (t + 1 < NT);

    // -------- phase 0: quadrant (row-half 0, col-half 0)
    asm volatile("s_waitcnt vmcnt(4)" ::: "memory");
    __builtin_amdgcn_sched_barrier(0);
    __builtin_amdgcn_s_barrier();
    __builtin_amdgcn_sched_barrier(0);
#pragma unroll
    for (int m = 0; m < 4; ++m) {
      const int ar = wm * 128 + m * 16 + lrow;
#pragma unroll
      for (int kk = 0; kk < 2; ++kk)
        af[m][kk] = *reinterpret_cast<const bf16x8*>(
            Ab + ar * 128 + ((kk * 64 + lhi * 16) ^ xr));
    }
#pragma unroll
    for (int nn = 0; nn < 2; ++nn) {
      const int br = wn * 64 + nn * 16 + lrow;
#pragma unroll
      for (int kk = 0; kk < 2; ++kk)
        bf[0][nn][kk] = *reinterpret_cast<const bf16x8*>(
            Bb + br * 128 + ((kk * 64 + lhi * 16) ^ xr));
    }
    if (st) stage_half(As2, An, tid);
    __builtin_amdgcn_s_setprio(1);
#pragma unroll
    for (int kk = 0; kk < 2; ++kk)
#pragma unroll
      for (int m = 0; m < 4; ++m)
#pragma unroll
        for (int nn = 0; nn < 2; ++nn)
          acc[m][nn] = __builtin_amdgcn_mfma_f32_16x16x32_bf16(
              af[m][kk], bf[0][nn][kk], acc[m][nn], 0, 0, 0);
    __builtin_amdgcn_s_setprio(0);

    // -------- phase 1: (row-half 0, col-half 1)
    if (st) { asm volatile("s_waitcnt vmcnt(2)" ::: "memory"); }
    else    { asm volatile("s_waitcnt vmcnt(0)" ::: "memory"); }
    __builtin_amdgcn_sched_barrier(0);
    __builtin_amdgcn_s_barrier();
    __builtin_amdgcn_sched_barrier(0);
#pragma unroll
    for (int nn = 0; nn < 2; ++nn) {
      const int br = wn * 64 + 32 + nn * 16 + lrow;
#pragma unroll
      for (int kk = 0; kk < 2; ++kk)
        bf[1][nn][kk] = *reinterpret_cast<const bf16x8*>(
            Bb + br * 128 + ((kk * 64 + lhi * 16) ^ xr));
    }
    if (st) stage_half(Ws2, Bn, tid);
    __builtin_amdgcn_s_setprio(1);
#pragma unroll
    for (int kk = 0; kk < 2; ++kk)
#pragma unroll
      for (int m = 0; m < 4; ++m)
#pragma unroll
        for (int nn = 0; nn < 2; ++nn)
          acc[m][2 + nn] = __builtin_amdgcn_mfma_f32_16x16x32_bf16(
              af[m][kk], bf[1][nn][kk], acc[m][2 + nn], 0, 0, 0);
    __builtin_amdgcn_s_setprio(0);

    // -------- phase 2: (row-half 1, col-half 0)  [A1 certified by ph1 wait]
#pragma unroll
    for (int m = 0; m < 4; ++m) {
      const int ar = wm * 128 + 64 + m * 16 + lrow;
#pragma unroll
      for (int kk = 0; kk < 2; ++kk)
        af[m][kk] = *reinterpret_cast<const bf16x8*>(
            Ab + ar * 128 + ((kk * 64 + lhi * 16) ^ xr));
    }
    if (st) stage_half(As2 + 128 * 1024, An + 16384, tid);
    __builtin_amdgcn_s_setprio(1);
#pragma unroll
    for (int kk = 0; kk < 2; ++kk)
#pragma unroll
      for (int m = 0; m < 4; ++m)
#pragma unroll
        for (int nn = 0; nn < 2; ++nn)
          acc[4 + m][nn] = __builtin_amdgcn_mfma_f32_16x16x32_bf16(
              af[m][kk], bf[0][nn][kk], acc[4 + m][nn], 0, 0, 0);
    __builtin_amdgcn_s_setprio(0);

    // -------- phase 3: (row-half 1, col-half 1)
    if (st) stage_half(Ws2 + 128 * 1024, Bn + 16384, tid);
    __builtin_amdgcn_s_setprio(1);
#pragma unroll
    for (int kk = 0; kk < 2; ++kk)
#pragma unroll
      for (int m = 0; m < 4; ++m)
#pragma unroll
        for (int nn = 0; nn < 2; ++nn)
          acc[4 + m][2 + nn] = __builtin_amdgcn_mfma_f32_16x16x32_bf16(
              af[m][kk], bf[1][nn][kk], acc[4 + m][2 + nn], 0, 0, 0);
    __builtin_amdgcn_s_setprio(0);
  }

  // -------- epilogue
  const int row0 = tm * 256 + wm * 128;
  if constexpr (MODE == 0) {
    const int sel = tn >> 2;                  // 0:Q 1:K 2:V
    const int col0 = (tn & 3) * 256 + wn * 64;
    const float* bias = sel == 0 ? b0 : sel == 1 ? b1 : b2;
    float bv4[4];
#pragma unroll
    for (int ng = 0; ng < 4; ++ng) bv4[ng] = bias[col0 + ng * 16 + lrow];
#pragma unroll
    for (int mg = 0; mg < 8; ++mg)
#pragma unroll
      for (int ng = 0; ng < 4; ++ng)
#pragma unroll
        for (int i = 0; i < 4; ++i) {
          const int row = row0 + mg * 16 + lhi * 4 + i;
          const int col = col0 + ng * 16 + lrow;
          const float v = acc[mg][ng][i] + bv4[ng];
          if (sel == 0) {
            ((__hip_bfloat16*)O0)[(size_t)row * 1024 + col] =
                __float2bfloat16(v * 0.18033688011112042f);
          } else if (sel == 1) {
            ((__hip_bfloat16*)O1)[(size_t)row * 1024 + col] = __float2bfloat16(v);
          } else {
            const int tt = row & 2047, bb = row >> 11;
            ((__hip_bfloat16*)O2)[((size_t)((bb * 16 + (col >> 6)) * 64 +
                                            (col & 63))) * 2048 + tt] =
                __float2bfloat16(v);
          }
        }
  } else {
    const int col0 = tn * 256 + wn * 64;
    float bv4[4];
#pragma unroll
    for (int ng = 0; ng < 4; ++ng) bv4[ng] = b0[col0 + ng * 16 + lrow];
#pragma unroll
    for (int mg = 0; mg < 8; ++mg)
#pragma unroll
      for (int ng = 0; ng < 4; ++ng)
#pragma unroll
        for (int i = 0; i < 4; ++i) {
          const int row = row0 + mg * 16 + lhi * 4 + i;
          const int col = col0 + ng * 16 + lrow;
          ((float*)O0)[(size_t)row * 1024 + col] = acc[mg][ng][i] + bv4[ng];
        }
  }
}

// ---------------- flash attention (unchanged from R6) ----------------------
__device__ __forceinline__ void stage_kv(char* __restrict__ smem, int buf,
                                         const __hip_bfloat16* __restrict__ Kb,
                                         const __hip_bfloat16* __restrict__ Vb,
                                         int kv0, int tid) {
  const int w = tid >> 6, l = tid & 63;
  char* base = smem + buf * 16384;
#pragma unroll
  for (int s = 0; s < 2; ++s) {
    const int c = s * 256 + w * 64 + l;
    const int row = c >> 3;
    const int scb = ((c & 7) << 4) ^ ((row & 7) << 4);
    __builtin_amdgcn_global_load_lds(
        (const __attribute__((address_space(1))) void*)(Kb + (size_t)(kv0 + row) * 1024 + (scb >> 1)),
        (__attribute__((address_space(3))) void*)(base + s * 4096 + w * 1024), 16, 0, 0);
  }
#pragma unroll
  for (int s = 0; s < 2; ++s) {
    const int c = s * 256 + w * 64 + l;
    const int row = c >> 3;
    const int scb = ((c & 7) << 4) ^ ((row & 7) << 4);
    __builtin_amdgcn_global_load_lds(
        (const __attribute__((address_space(1))) void*)(Vb + (size_t)row * 2048 + kv0 + (scb >> 1)),
        (__attribute__((address_space(3))) void*)(base + 8192 + s * 4096 + w * 1024), 16, 0, 0);
  }
}

template <bool MASKED>
__device__ __forceinline__ void attn_step(
    int kv0, int q0w, int lrow, int lhi, const char* __restrict__ kvb,
    const bf16x8 qf[2][2], f32x4 o[2][4], float m[2], float l[2],
    __hip_bfloat16* __restrict__ P) {
  constexpr float TH = 8.0f;
  const int xr = (lrow & 7) << 4;
  f32x4 s[2][4] = {};
  __builtin_amdgcn_s_setprio(1);
#pragma unroll
  for (int g = 0; g < 4; ++g) {
    const char* rowp = kvb + (g * 16 + lrow) * 128;
#pragma unroll
    for (int kk = 0; kk < 2; ++kk) {
      bf16x8 kf = *reinterpret_cast<const bf16x8*>(rowp + ((kk * 64 + lhi * 16) ^ xr));
#pragma unroll
      for (int j = 0; j < 2; ++j)
        s[j][g] = __builtin_amdgcn_mfma_f32_16x16x32_bf16(kf, qf[j][kk], s[j][g], 0, 0, 0);
    }
  }
  __builtin_amdgcn_s_setprio(0);
  float mx[2];
#pragma unroll
  for (int j = 0; j < 2; ++j) {
    if (MASKED) {
#pragma unroll
      for (int g = 0; g < 4; ++g)
#pragma unroll
        for (int i = 0; i < 4; ++i) {
          const int k = kv0 + g * 16 + lhi * 4 + i;
          if (k > q0w + j * 16 + lrow) s[j][g][i] = -1e30f;
        }
    }
    float gm[4];
#pragma unroll
    for (int g = 0; g < 4; ++g)
      gm[g] = fmaxf(fmaxf(s[j][g][0], s[j][g][1]), fmaxf(s[j][g][2], s[j][g][3]));
    float t = fmaxf(fmaxf(gm[0], gm[1]), fmaxf(gm[2], gm[3]));
    t = fmaxf(t, __shfl_xor(t, 16));
    t = fmaxf(t, __shfl_xor(t, 32));
    mx[j] = t;
  }
  const int need = (mx[0] > m[0] + TH) || (mx[1] > m[1] + TH);
  if (__any(need)) {
#pragma unroll
    for (int j = 0; j < 2; ++j) {
      const float nm = fmaxf(m[j], mx[j]);
      const float al = exp2f(m[j] - nm);
      m[j] = nm;
      l[j] *= al;
      float a4[4];
#pragma unroll
      for (int i = 0; i < 4; ++i) a4[i] = __shfl(al, 4 * lhi + i, 16);
#pragma unroll
      for (int f = 0; f < 4; ++f)
#pragma unroll
        for (int i = 0; i < 4; ++i) o[j][f][i] *= a4[i];
    }
  }
#pragma unroll
  for (int j = 0; j < 2; ++j) {
    float gs[4];
#pragma unroll
    for (int g = 0; g < 4; ++g) {
      bf16x4_s t4;
      float p0 = exp2f(s[j][g][0] - m[j]);
      float p1 = exp2f(s[j][g][1] - m[j]);
      float p2 = exp2f(s[j][g][2] - m[j]);
      float p3 = exp2f(s[j][g][3] - m[j]);
      t4.h[0] = __float2bfloat16(p0); t4.h[1] = __float2bfloat16(p1);
      t4.h[2] = __float2bfloat16(p2); t4.h[3] = __float2bfloat16(p3);
      gs[g] = (p0 + p1) + (p2 + p3);
      *reinterpret_cast<bf16x4_s*>(P + (j * 16 + lrow) * 72 + g * 16 + lhi * 4) = t4;
    }
    float sum = (gs[0] + gs[1]) + (gs[2] + gs[3]);
    sum += __shfl_xor(sum, 16);
    sum += __shfl_xor(sum, 32);
    l[j] += sum;
  }
  bf16x8 pf[2][2];
#pragma unroll
  for (int j = 0; j < 2; ++j)
#pragma unroll
    for (int n = 0; n < 2; ++n)
      pf[j][n] = *reinterpret_cast<const bf16x8*>(P + (j * 16 + lrow) * 72 + n * 32 + lhi * 8);
  __builtin_amdgcn_s_setprio(1);
#pragma unroll
  for (int n = 0; n < 2; ++n)
#pragma unroll
    for (int f = 0; f < 4; ++f) {
      bf16x8 vf = *reinterpret_cast<const bf16x8*>(
          kvb + 8192 + (f * 16 + lrow) * 128 + ((n * 64 + lhi * 16) ^ xr));
#pragma unroll
      for (int j = 0; j < 2; ++j)
        o[j][f] = __builtin_amdgcn_mfma_f32_16x16x32_bf16(pf[j][n], vf, o[j][f], 0, 0, 0);
    }
  __builtin_amdgcn_s_setprio(0);
}

__global__ __launch_bounds__(256, 3) void attn_fwd(
    const __hip_bfloat16* __restrict__ Q, const __hip_bfloat16* __restrict__ Km,
    const __hip_bfloat16* __restrict__ Vt, __hip_bfloat16* __restrict__ Y) {
  constexpr int T = 2048, C = 1024, D = 64;
  const int tid = threadIdx.x;
  const int wid = tid >> 6;
  const int lane = tid & 63;
  const int lrow = lane & 15;
  const int lhi = lane >> 4;
  const int n = blockIdx.x;
  const int xcd = n & 7;
  const int w8 = n >> 3;
  const int j2 = w8 >> 5;
  const int r = w8 & 31;
  const int s5 = r >> 3;
  const int bh = xcd * 8 + (r & 7);
  int p;
  if (j2 == 0) p = s5;
  else if (j2 == 1) p = 3 - s5;
  else if (j2 == 2) p = s5 ^ 1;
  else p = 3 - (s5 ^ 1);
  const int qt = 15 - (j2 * 4 + p);
  const int b = bh >> 4, h = bh & 15;
  const int q0w = qt * 128 + wid * 32;

  const __hip_bfloat16* Qb = Q + ((size_t)b * T) * C + h * D;
  const __hip_bfloat16* Kb = Km + ((size_t)b * T) * C + h * D;
  const __hip_bfloat16* Vb = Vt + (size_t)bh * D * T;

  __shared__ char smem[51200];
  __hip_bfloat16* P = (__hip_bfloat16*)(smem + 32768 + wid * 4608);

  bf16x8 qf[2][2];
#pragma unroll
  for (int j = 0; j < 2; ++j)
#pragma unroll
    for (int kk = 0; kk < 2; ++kk)
      qf[j][kk] = *reinterpret_cast<const bf16x8*>(
          Qb + (size_t)(q0w + j * 16 + lrow) * C + kk * 32 + lhi * 8);

  f32x4 o[2][4] = {};
  float m[2] = {-1e30f, -1e30f}, l[2] = {0.f, 0.f};

  const int nt = 2 * qt + 2;
  const int ns = (q0w >> 6) + 1;

  stage_kv(smem, 0, Kb, Vb, 0, tid);
  for (int t = 0; t < nt; ++t) {
    __syncthreads();
    if (t + 1 < nt) stage_kv(smem, (t + 1) & 1, Kb, Vb, (t + 1) * 64, tid);
    if (t < ns) {
      const char* kvb = smem + (t & 1) * 16384;
      if (t == ns - 1)
        attn_step<true>(t * 64, q0w, lrow, lhi, kvb, qf, o, m, l, P);
      else
        attn_step<false>(t * 64, q0w, lrow, lhi, kvb, qf, o, m, l, P);
    }
  }

#pragma unroll
  for (int j = 0; j < 2; ++j) {
    float l4[4];
#pragma unroll
    for (int i = 0; i < 4; ++i) l4[i] = __shfl(l[j], 4 * lhi + i, 16);
#pragma unroll
    for (int f = 0; f < 4; ++f)
#pragma unroll
      for (int i = 0; i < 4; ++i) {
        const int row = q0w + j * 16 + 4 * lhi + i;
        Y[((size_t)b * T + row) * C + h * D + f * 16 + lrow] =
            __float2bfloat16(o[j][f][i] / l4[i]);
      }
  }
}

// ---------------- host launch ----------------------------------------------
extern "C" void kernel_launch(void* const* d_in, const int* in_sizes, int n_in,
                              void* d_out, int out_size, void* d_ws,
                              size_t ws_size, hipStream_t stream) {
  const float* x = (const float*)d_in[0];
  const float* Wq = (const float*)d_in[1];
  const float* bq = (const float*)d_in[2];
  const float* Wk = (const float*)d_in[3];
  const float* bk = (const float*)d_in[4];
  const float* Wv = (const float*)d_in[5];
  const float* bv = (const float*)d_in[6];
  const float* Wp = (const float*)d_in[7];
  const float* bp = (const float*)d_in[8];
  float* out = (float*)d_out;

  __hip_bfloat16* ws = (__hip_bfloat16*)d_ws;
  __hip_bfloat16* xb = ws;                   // 8388608
  __hip_bfloat16* wqb = xb + 8388608;        // 4 x 1048576, contiguous
  __hip_bfloat16* wpb = wqb + 3 * 1048576;
  __hip_bfloat16* Qs = wqb + 4 * 1048576;    // 8388608
  __hip_bfloat16* Ks = Qs + 8388608;
  __hip_bfloat16* Vts = Ks + 8388608;        // V^T: [B*H*64][2048]
  __hip_bfloat16* Ys = Vts + 8388608;        // attn out [B*T][C]

  cvt_kernel<<<4096, 256, 0, stream>>>(x, xb, 1048576);
  cvt4_kernel<<<2048, 256, 0, stream>>>(Wq, Wk, Wv, Wp, wqb);

  // QKV: M=8192, N=3072 -> 32x12 = 384 blocks (384%8==0, NB8=48)
  gemm256<0><<<dim3(384), 512, 0, stream>>>(xb, wqb, bq, bk, bv, Qs, Ks, Vts,
                                            12, 48);

  attn_fwd<<<dim3(1024), 256, 0, stream>>>(Qs, Ks, Vts, Ys);

  // proj: M=8192, N=1024 -> 32x4 = 128 blocks (NB8=16)
  gemm256<1><<<dim3(128), 512, 0, stream>>>(Ys, wpb, bp, nullptr, nullptr, out,
                                            nullptr, nullptr, 4, 16);
}

// Round 9
// 188.836 us; speedup vs baseline: 1.4254x; 1.0683x over previous
//
#include <hip/hip_runtime.h>
#include <hip/hip_bf16.h>

typedef __attribute__((ext_vector_type(8))) short bf16x8;
typedef __attribute__((ext_vector_type(4))) float f32x4;

struct bf16x8_s { __hip_bfloat16 h[8]; };
struct bf16x4_s { __hip_bfloat16 h[4]; };

// ---------------- fp32 -> bf16 conversion (8 elems/thread) ----------------
__global__ void cvt_kernel(const float* __restrict__ in,
                           __hip_bfloat16* __restrict__ out, int n8) {
  int i = blockIdx.x * blockDim.x + threadIdx.x;
  if (i >= n8) return;
  const float4* p = reinterpret_cast<const float4*>(in) + (size_t)i * 2;
  float4 a = p[0], b = p[1];
  bf16x8_s o;
  o.h[0] = __float2bfloat16(a.x); o.h[1] = __float2bfloat16(a.y);
  o.h[2] = __float2bfloat16(a.z); o.h[3] = __float2bfloat16(a.w);
  o.h[4] = __float2bfloat16(b.x); o.h[5] = __float2bfloat16(b.y);
  o.h[6] = __float2bfloat16(b.z); o.h[7] = __float2bfloat16(b.w);
  *reinterpret_cast<bf16x8_s*>(out + (size_t)i * 8) = o;
}

__global__ void cvt4_kernel(const float* __restrict__ w0,
                            const float* __restrict__ w1,
                            const float* __restrict__ w2,
                            const float* __restrict__ w3,
                            __hip_bfloat16* __restrict__ out) {
  const int bid = blockIdx.x;
  const int seg = bid >> 9;
  const int i = (bid & 511) * 256 + threadIdx.x;
  const float* src = seg == 0 ? w0 : seg == 1 ? w1 : seg == 2 ? w2 : w3;
  const float4* p = reinterpret_cast<const float4*>(src) + (size_t)i * 2;
  float4 a = p[0], b = p[1];
  bf16x8_s o;
  o.h[0] = __float2bfloat16(a.x); o.h[1] = __float2bfloat16(a.y);
  o.h[2] = __float2bfloat16(a.z); o.h[3] = __float2bfloat16(a.w);
  o.h[4] = __float2bfloat16(b.x); o.h[5] = __float2bfloat16(b.y);
  o.h[6] = __float2bfloat16(b.z); o.h[7] = __float2bfloat16(b.w);
  *reinterpret_cast<bf16x8_s*>(out + (size_t)seg * 1048576 + (size_t)i * 8) = o;
}

// ---------------- 128x128 GEMM (m97 structure + T2 swizzle + coalesced epi) -
// 256 thr = 4 waves (2x2), per-wave 64x64 out, BK=64, K=1024.
// LDS 32 KB (A 16K + W 16K), single-buffered m97 2-barrier loop ->
// 4 blocks/CU co-resident (implicit overlap). Staging: global_load_lds with
// linear LDS dest + inverse-XOR-swizzled source; fragment reads apply the
// same XOR -> 0 bank conflicts. Epilogue: per-wave LDS slice (reuse staging
// LDS after final barrier) -> 16-B coalesced global stores.
__device__ __forceinline__ void stage_tile(const __hip_bfloat16* src,
                                           char* lds, int tid) {
#pragma unroll
  for (int s = 0; s < 4; ++s) {
    const int c = s * 256 + tid;           // 0..1023 -> (row, 16B-seg)
    const int row = c >> 3;
    const int cb = (((c & 7) << 4) ^ ((row & 7) << 4));
    __builtin_amdgcn_global_load_lds(
        (const __attribute__((address_space(1))) void*)((const char*)(src + (size_t)row * 1024) + cb),
        (__attribute__((address_space(3))) void*)(lds + s * 4096 + (tid & 192) * 16),
        16, 0, 0);
  }
}

// MODE 0: fused QKV (tn 0..23; sel=tn>>3: Q scaled / K / V-transposed, bf16)
// MODE 1: projection (tn 0..7; fp32 out + bias)
template <int MODE>
__global__ __launch_bounds__(256) void gemm128(
    const __hip_bfloat16* __restrict__ A, const __hip_bfloat16* __restrict__ W,
    const float* __restrict__ b0, const float* __restrict__ b1,
    const float* __restrict__ b2, void* __restrict__ O0,
    void* __restrict__ O1, void* __restrict__ O2) {
  constexpr float SC = 0.18033688011112042f;  // 0.125 * log2(e)
  __shared__ char smem[32768];
  const int tid = threadIdx.x;
  const int lane = tid & 63;
  const int lrow = lane & 15;
  const int lhi = lane >> 4;
  const int wid = tid >> 6;
  const int wm = wid >> 1, wn = wid & 1;
  const int xr = (lrow & 7) << 4;

  // bijective XCD swizzle: each XCD owns a contiguous wg range (3 or 1
  // W-panels -> W L2-resident, A panels reused 3x / streamed).
  const int n = blockIdx.x;
  const int wg = MODE == 0 ? (n & 7) * 192 + (n >> 3) : (n & 7) * 64 + (n >> 3);
  const int tm = wg & 63;
  const int tn = wg >> 6;
  const int row0 = tm * 128;

  const __hip_bfloat16* Ap = A + (size_t)row0 * 1024;
  const __hip_bfloat16* Wp = W + (size_t)(tn * 128) * 1024;

  f32x4 acc[4][4] = {};

  for (int k0 = 0; k0 < 1024; k0 += 64) {
    stage_tile(Ap + k0, smem, tid);
    stage_tile(Wp + k0, smem + 16384, tid);
    __syncthreads();
    bf16x8 af[4][2], bfr[4][2];
#pragma unroll
    for (int m = 0; m < 4; ++m) {
      const int ar = wm * 64 + m * 16 + lrow;
#pragma unroll
      for (int kk = 0; kk < 2; ++kk)
        af[m][kk] = *reinterpret_cast<const bf16x8*>(
            smem + ar * 128 + ((kk * 64 + lhi * 16) ^ xr));
    }
#pragma unroll
    for (int nn = 0; nn < 4; ++nn) {
      const int br = wn * 64 + nn * 16 + lrow;
#pragma unroll
      for (int kk = 0; kk < 2; ++kk)
        bfr[nn][kk] = *reinterpret_cast<const bf16x8*>(
            smem + 16384 + br * 128 + ((kk * 64 + lhi * 16) ^ xr));
    }
    __builtin_amdgcn_s_setprio(1);
#pragma unroll
    for (int kk = 0; kk < 2; ++kk)
#pragma unroll
      for (int m = 0; m < 4; ++m)
#pragma unroll
        for (int nn = 0; nn < 4; ++nn)
          acc[m][nn] = __builtin_amdgcn_mfma_f32_16x16x32_bf16(
              af[m][kk], bfr[nn][kk], acc[m][nn], 0, 0, 0);
    __builtin_amdgcn_s_setprio(0);
    __syncthreads();
  }

  // ---- epilogue: per-wave 8 KB LDS slice (all staging reads retired)
  char* epi = smem + wid * 8192;
  const int grow0 = row0 + wm * 64;

  if constexpr (MODE == 0) {
    const int sel = tn >> 3;                       // 0:Q 1:K 2:V
    const int cloc = (tn & 7) * 128 + wn * 64;     // col in [0,1024)
    const float* bias = sel == 0 ? b0 : sel == 1 ? b1 : b2;
    float bv4[4];
#pragma unroll
    for (int nn = 0; nn < 4; ++nn) bv4[nn] = bias[cloc + nn * 16 + lrow];

    if (sel != 2) {
      __hip_bfloat16* dst = sel == 0 ? (__hip_bfloat16*)O0 : (__hip_bfloat16*)O1;
#pragma unroll
      for (int mg = 0; mg < 4; ++mg) {
        // 16x64 bf16 tile, LDS stride 72 elems (bank-spread)
#pragma unroll
        for (int nn = 0; nn < 4; ++nn)
#pragma unroll
          for (int i = 0; i < 4; ++i) {
            float v = acc[mg][nn][i] + bv4[nn];
            if (sel == 0) v *= SC;
            ((__hip_bfloat16*)epi)[(lhi * 4 + i) * 72 + nn * 16 + lrow] =
                __float2bfloat16(v);
          }
#pragma unroll
        for (int ps = 0; ps < 2; ++ps) {
          const int r = ps * 8 + (lane >> 3);
          bf16x8 val = *reinterpret_cast<const bf16x8*>(epi + r * 144 + (lane & 7) * 16);
          const int grow = grow0 + mg * 16 + r;
          *reinterpret_cast<bf16x8*>(&dst[(size_t)grow * 1024 + cloc + (lane & 7) * 8]) = val;
        }
      }
    } else {
      // V^T: out[((b*16+h)*64 + d)*2048 + t]; wave covers one h, d=0..63
      __hip_bfloat16* dst = (__hip_bfloat16*)O2;
      const int h = cloc >> 6;
      const int bb = grow0 >> 11;
      const int t0 = grow0 & 2047;
      __hip_bfloat16* vb = dst + ((size_t)(bb * 16 + h) * 64) * 2048;
#pragma unroll
      for (int ng = 0; ng < 4; ++ng) {
        // transpose into LDS: [16 d][72-stride t]
#pragma unroll
        for (int m = 0; m < 4; ++m)
#pragma unroll
          for (int i = 0; i < 4; ++i) {
            const float v = acc[m][ng][i] + bv4[ng];
            ((__hip_bfloat16*)epi)[lrow * 72 + m * 16 + lhi * 4 + i] =
                __float2bfloat16(v);
          }
#pragma unroll
        for (int ps = 0; ps < 2; ++ps) {
          const int dr = ps * 8 + (lane >> 3);
          bf16x8 val = *reinterpret_cast<const bf16x8*>(epi + dr * 144 + (lane & 7) * 16);
          const int d = ng * 16 + dr;
          *reinterpret_cast<bf16x8*>(&vb[(size_t)d * 2048 + t0 + (lane & 7) * 8]) = val;
        }
      }
    }
  } else {
    // projection: fp32 row-major + bias
    float* dst = (float*)O0;
    const int cloc = tn * 128 + wn * 64;
    float bv4[4];
#pragma unroll
    for (int nn = 0; nn < 4; ++nn) bv4[nn] = b0[cloc + nn * 16 + lrow];
#pragma unroll
    for (int mg = 0; mg < 4; ++mg) {
#pragma unroll
      for (int nn = 0; nn < 4; ++nn)
#pragma unroll
        for (int i = 0; i < 4; ++i)
          ((float*)epi)[(lhi * 4 + i) * 68 + nn * 16 + lrow] =
              acc[mg][nn][i] + bv4[nn];
#pragma unroll
      for (int ps = 0; ps < 4; ++ps) {
        const int r = ps * 4 + (lane >> 4);
        float4 val = *reinterpret_cast<const float4*>(epi + r * 272 + (lane & 15) * 16);
        const int grow = grow0 + mg * 16 + r;
        *reinterpret_cast<float4*>(&dst[(size_t)grow * 1024 + cloc + (lane & 15) * 4]) = val;
      }
    }
  }
}

// ---------------- flash attention (unchanged from R6) ----------------------
__device__ __forceinline__ void stage_kv(char* __restrict__ smem, int buf,
                                         const __hip_bfloat16* __restrict__ Kb,
                                         const __hip_bfloat16* __restrict__ Vb,
                                         int kv0, int tid) {
  const int w = tid >> 6, l = tid & 63;
  char* base = smem + buf * 16384;
#pragma unroll
  for (int s = 0; s < 2; ++s) {
    const int c = s * 256 + w * 64 + l;
    const int row = c >> 3;
    const int scb = ((c & 7) << 4) ^ ((row & 7) << 4);
    __builtin_amdgcn_global_load_lds(
        (const __attribute__((address_space(1))) void*)(Kb + (size_t)(kv0 + row) * 1024 + (scb >> 1)),
        (__attribute__((address_space(3))) void*)(base + s * 4096 + w * 1024), 16, 0, 0);
  }
#pragma unroll
  for (int s = 0; s < 2; ++s) {
    const int c = s * 256 + w * 64 + l;
    const int row = c >> 3;
    const int scb = ((c & 7) << 4) ^ ((row & 7) << 4);
    __builtin_amdgcn_global_load_lds(
        (const __attribute__((address_space(1))) void*)(Vb + (size_t)row * 2048 + kv0 + (scb >> 1)),
        (__attribute__((address_space(3))) void*)(base + 8192 + s * 4096 + w * 1024), 16, 0, 0);
  }
}

template <bool MASKED>
__device__ __forceinline__ void attn_step(
    int kv0, int q0w, int lrow, int lhi, const char* __restrict__ kvb,
    const bf16x8 qf[2][2], f32x4 o[2][4], float m[2], float l[2],
    __hip_bfloat16* __restrict__ P) {
  constexpr float TH = 8.0f;
  const int xr = (lrow & 7) << 4;
  f32x4 s[2][4] = {};
  __builtin_amdgcn_s_setprio(1);
#pragma unroll
  for (int g = 0; g < 4; ++g) {
    const char* rowp = kvb + (g * 16 + lrow) * 128;
#pragma unroll
    for (int kk = 0; kk < 2; ++kk) {
      bf16x8 kf = *reinterpret_cast<const bf16x8*>(rowp + ((kk * 64 + lhi * 16) ^ xr));
#pragma unroll
      for (int j = 0; j < 2; ++j)
        s[j][g] = __builtin_amdgcn_mfma_f32_16x16x32_bf16(kf, qf[j][kk], s[j][g], 0, 0, 0);
    }
  }
  __builtin_amdgcn_s_setprio(0);
  float mx[2];
#pragma unroll
  for (int j = 0; j < 2; ++j) {
    if (MASKED) {
#pragma unroll
      for (int g = 0; g < 4; ++g)
#pragma unroll
        for (int i = 0; i < 4; ++i) {
          const int k = kv0 + g * 16 + lhi * 4 + i;
          if (k > q0w + j * 16 + lrow) s[j][g][i] = -1e30f;
        }
    }
    float gm[4];
#pragma unroll
    for (int g = 0; g < 4; ++g)
      gm[g] = fmaxf(fmaxf(s[j][g][0], s[j][g][1]), fmaxf(s[j][g][2], s[j][g][3]));
    float t = fmaxf(fmaxf(gm[0], gm[1]), fmaxf(gm[2], gm[3]));
    t = fmaxf(t, __shfl_xor(t, 16));
    t = fmaxf(t, __shfl_xor(t, 32));
    mx[j] = t;
  }
  const int need = (mx[0] > m[0] + TH) || (mx[1] > m[1] + TH);
  if (__any(need)) {
#pragma unroll
    for (int j = 0; j < 2; ++j) {
      const float nm = fmaxf(m[j], mx[j]);
      const float al = exp2f(m[j] - nm);
      m[j] = nm;
      l[j] *= al;
      float a4[4];
#pragma unroll
      for (int i = 0; i < 4; ++i) a4[i] = __shfl(al, 4 * lhi + i, 16);
#pragma unroll
      for (int f = 0; f < 4; ++f)
#pragma unroll
        for (int i = 0; i < 4; ++i) o[j][f][i] *= a4[i];
    }
  }
#pragma unroll
  for (int j = 0; j < 2; ++j) {
    float gs[4];
#pragma unroll
    for (int g = 0; g < 4; ++g) {
      bf16x4_s t4;
      float p0 = exp2f(s[j][g][0] - m[j]);
      float p1 = exp2f(s[j][g][1] - m[j]);
      float p2 = exp2f(s[j][g][2] - m[j]);
      float p3 = exp2f(s[j][g][3] - m[j]);
      t4.h[0] = __float2bfloat16(p0); t4.h[1] = __float2bfloat16(p1);
      t4.h[2] = __float2bfloat16(p2); t4.h[3] = __float2bfloat16(p3);
      gs[g] = (p0 + p1) + (p2 + p3);
      *reinterpret_cast<bf16x4_s*>(P + (j * 16 + lrow) * 72 + g * 16 + lhi * 4) = t4;
    }
    float sum = (gs[0] + gs[1]) + (gs[2] + gs[3]);
    sum += __shfl_xor(sum, 16);
    sum += __shfl_xor(sum, 32);
    l[j] += sum;
  }
  bf16x8 pf[2][2];
#pragma unroll
  for (int j = 0; j < 2; ++j)
#pragma unroll
    for (int n = 0; n < 2; ++n)
      pf[j][n] = *reinterpret_cast<const bf16x8*>(P + (j * 16 + lrow) * 72 + n * 32 + lhi * 8);
  __builtin_amdgcn_s_setprio(1);
#pragma unroll
  for (int n = 0; n < 2; ++n)
#pragma unroll
    for (int f = 0; f < 4; ++f) {
      bf16x8 vf = *reinterpret_cast<const bf16x8*>(
          kvb + 8192 + (f * 16 + lrow) * 128 + ((n * 64 + lhi * 16) ^ xr));
#pragma unroll
      for (int j = 0; j < 2; ++j)
        o[j][f] = __builtin_amdgcn_mfma_f32_16x16x32_bf16(pf[j][n], vf, o[j][f], 0, 0, 0);
    }
  __builtin_amdgcn_s_setprio(0);
}

__global__ __launch_bounds__(256, 3) void attn_fwd(
    const __hip_bfloat16* __restrict__ Q, const __hip_bfloat16* __restrict__ Km,
    const __hip_bfloat16* __restrict__ Vt, __hip_bfloat16* __restrict__ Y) {
  constexpr int T = 2048, C = 1024, D = 64;
  const int tid = threadIdx.x;
  const int wid = tid >> 6;
  const int lane = tid & 63;
  const int lrow = lane & 15;
  const int lhi = lane >> 4;
  const int n = blockIdx.x;
  const int xcd = n & 7;
  const int w8 = n >> 3;
  const int j2 = w8 >> 5;
  const int r = w8 & 31;
  const int s5 = r >> 3;
  const int bh = xcd * 8 + (r & 7);
  int p;
  if (j2 == 0) p = s5;
  else if (j2 == 1) p = 3 - s5;
  else if (j2 == 2) p = s5 ^ 1;
  else p = 3 - (s5 ^ 1);
  const int qt = 15 - (j2 * 4 + p);
  const int b = bh >> 4, h = bh & 15;
  const int q0w = qt * 128 + wid * 32;

  const __hip_bfloat16* Qb = Q + ((size_t)b * T) * C + h * D;
  const __hip_bfloat16* Kb = Km + ((size_t)b * T) * C + h * D;
  const __hip_bfloat16* Vb = Vt + (size_t)bh * D * T;

  __shared__ char smem[51200];
  __hip_bfloat16* P = (__hip_bfloat16*)(smem + 32768 + wid * 4608);

  bf16x8 qf[2][2];
#pragma unroll
  for (int j = 0; j < 2; ++j)
#pragma unroll
    for (int kk = 0; kk < 2; ++kk)
      qf[j][kk] = *reinterpret_cast<const bf16x8*>(
          Qb + (size_t)(q0w + j * 16 + lrow) * C + kk * 32 + lhi * 8);

  f32x4 o[2][4] = {};
  float m[2] = {-1e30f, -1e30f}, l[2] = {0.f, 0.f};

  const int nt = 2 * qt + 2;
  const int ns = (q0w >> 6) + 1;

  stage_kv(smem, 0, Kb, Vb, 0, tid);
  for (int t = 0; t < nt; ++t) {
    __syncthreads();
    if (t + 1 < nt) stage_kv(smem, (t + 1) & 1, Kb, Vb, (t + 1) * 64, tid);
    if (t < ns) {
      const char* kvb = smem + (t & 1) * 16384;
      if (t == ns - 1)
        attn_step<true>(t * 64, q0w, lrow, lhi, kvb, qf, o, m, l, P);
      else
        attn_step<false>(t * 64, q0w, lrow, lhi, kvb, qf, o, m, l, P);
    }
  }

#pragma unroll
  for (int j = 0; j < 2; ++j) {
    float l4[4];
#pragma unroll
    for (int i = 0; i < 4; ++i) l4[i] = __shfl(l[j], 4 * lhi + i, 16);
#pragma unroll
    for (int f = 0; f < 4; ++f)
#pragma unroll
      for (int i = 0; i < 4; ++i) {
        const int row = q0w + j * 16 + 4 * lhi + i;
        Y[((size_t)b * T + row) * C + h * D + f * 16 + lrow] =
            __float2bfloat16(o[j][f][i] / l4[i]);
      }
  }
}

// ---------------- host launch ----------------------------------------------
extern "C" void kernel_launch(void* const* d_in, const int* in_sizes, int n_in,
                              void* d_out, int out_size, void* d_ws,
                              size_t ws_size, hipStream_t stream) {
  const float* x = (const float*)d_in[0];
  const float* Wq = (const float*)d_in[1];
  const float* bq = (const float*)d_in[2];
  const float* Wk = (const float*)d_in[3];
  const float* bk = (const float*)d_in[4];
  const float* Wv = (const float*)d_in[5];
  const float* bv = (const float*)d_in[6];
  const float* Wp = (const float*)d_in[7];
  const float* bp = (const float*)d_in[8];
  float* out = (float*)d_out;

  __hip_bfloat16* ws = (__hip_bfloat16*)d_ws;
  __hip_bfloat16* xb = ws;                   // 8388608
  __hip_bfloat16* wqb = xb + 8388608;        // 4 x 1048576, contiguous
  __hip_bfloat16* wpb = wqb + 3 * 1048576;
  __hip_bfloat16* Qs = wqb + 4 * 1048576;    // 8388608
  __hip_bfloat16* Ks = Qs + 8388608;
  __hip_bfloat16* Vts = Ks + 8388608;        // V^T: [B*H*64][2048]
  __hip_bfloat16* Ys = Vts + 8388608;        // attn out [B*T][C]

  cvt_kernel<<<4096, 256, 0, stream>>>(x, xb, 1048576);
  cvt4_kernel<<<2048, 256, 0, stream>>>(Wq, Wk, Wv, Wp, wqb);

  // QKV: 64 row-tiles x 24 col-tiles = 1536 blocks (1536 % 8 == 0)
  gemm128<0><<<dim3(1536), 256, 0, stream>>>(xb, wqb, bq, bk, bv, Qs, Ks, Vts);

  attn_fwd<<<dim3(1024), 256, 0, stream>>>(Qs, Ks, Vts, Ys);

  // proj: 64 x 8 = 512 blocks
  gemm128<1><<<dim3(512), 256, 0, stream>>>(Ys, wpb, bp, nullptr, nullptr, out,
                                            nullptr, nullptr);
}

// Round 10
// 178.510 us; speedup vs baseline: 1.5079x; 1.0578x over previous
//
#include <hip/hip_runtime.h>
#include <hip/hip_bf16.h>

typedef __attribute__((ext_vector_type(8))) short bf16x8;
typedef __attribute__((ext_vector_type(4))) float f32x4;

struct bf16x8_s { __hip_bfloat16 h[8]; };
struct bf16x4_s { __hip_bfloat16 h[4]; };

#if defined(__has_builtin)
#if __has_builtin(__builtin_amdgcn_exp2f)
#define EXP2F(x) __builtin_amdgcn_exp2f(x)
#endif
#endif
#ifndef EXP2F
#define EXP2F(x) exp2f(x)
#endif

// ---------------- fp32 -> bf16 conversion (8 elems/thread) ----------------
__global__ void cvt_kernel(const float* __restrict__ in,
                           __hip_bfloat16* __restrict__ out, int n8) {
  int i = blockIdx.x * blockDim.x + threadIdx.x;
  if (i >= n8) return;
  const float4* p = reinterpret_cast<const float4*>(in) + (size_t)i * 2;
  float4 a = p[0], b = p[1];
  bf16x8_s o;
  o.h[0] = __float2bfloat16(a.x); o.h[1] = __float2bfloat16(a.y);
  o.h[2] = __float2bfloat16(a.z); o.h[3] = __float2bfloat16(a.w);
  o.h[4] = __float2bfloat16(b.x); o.h[5] = __float2bfloat16(b.y);
  o.h[6] = __float2bfloat16(b.z); o.h[7] = __float2bfloat16(b.w);
  *reinterpret_cast<bf16x8_s*>(out + (size_t)i * 8) = o;
}

__global__ void cvt4_kernel(const float* __restrict__ w0,
                            const float* __restrict__ w1,
                            const float* __restrict__ w2,
                            const float* __restrict__ w3,
                            __hip_bfloat16* __restrict__ out) {
  const int bid = blockIdx.x;
  const int seg = bid >> 9;
  const int i = (bid & 511) * 256 + threadIdx.x;
  const float* src = seg == 0 ? w0 : seg == 1 ? w1 : seg == 2 ? w2 : w3;
  const float4* p = reinterpret_cast<const float4*>(src) + (size_t)i * 2;
  float4 a = p[0], b = p[1];
  bf16x8_s o;
  o.h[0] = __float2bfloat16(a.x); o.h[1] = __float2bfloat16(a.y);
  o.h[2] = __float2bfloat16(a.z); o.h[3] = __float2bfloat16(a.w);
  o.h[4] = __float2bfloat16(b.x); o.h[5] = __float2bfloat16(b.y);
  o.h[6] = __float2bfloat16(b.z); o.h[7] = __float2bfloat16(b.w);
  *reinterpret_cast<bf16x8_s*>(out + (size_t)seg * 1048576 + (size_t)i * 8) = o;
}

// ---------------- 128x128 GEMM (m97 structure + T2 swizzle + coalesced epi) -
__device__ __forceinline__ void stage_tile(const __hip_bfloat16* src,
                                           char* lds, int tid) {
#pragma unroll
  for (int s = 0; s < 4; ++s) {
    const int c = s * 256 + tid;
    const int row = c >> 3;
    const int cb = (((c & 7) << 4) ^ ((row & 7) << 4));
    __builtin_amdgcn_global_load_lds(
        (const __attribute__((address_space(1))) void*)((const char*)(src + (size_t)row * 1024) + cb),
        (__attribute__((address_space(3))) void*)(lds + s * 4096 + (tid & 192) * 16),
        16, 0, 0);
  }
}

// MODE 0: fused QKV (tn 0..23; sel=tn>>3: Q scaled / K / V-transposed, bf16)
// MODE 1: projection (tn 0..7; fp32 out + bias)
template <int MODE>
__global__ __launch_bounds__(256) void gemm128(
    const __hip_bfloat16* __restrict__ A, const __hip_bfloat16* __restrict__ W,
    const float* __restrict__ b0, const float* __restrict__ b1,
    const float* __restrict__ b2, void* __restrict__ O0,
    void* __restrict__ O1, void* __restrict__ O2) {
  constexpr float SC = 0.18033688011112042f;  // 0.125 * log2(e)
  __shared__ char smem[32768];
  const int tid = threadIdx.x;
  const int lane = tid & 63;
  const int lrow = lane & 15;
  const int lhi = lane >> 4;
  const int wid = tid >> 6;
  const int wm = wid >> 1, wn = wid & 1;
  const int xr = (lrow & 7) << 4;

  const int n = blockIdx.x;
  const int wg = MODE == 0 ? (n & 7) * 192 + (n >> 3) : (n & 7) * 64 + (n >> 3);
  const int tm = wg & 63;
  const int tn = wg >> 6;
  const int row0 = tm * 128;

  const __hip_bfloat16* Ap = A + (size_t)row0 * 1024;
  const __hip_bfloat16* Wp = W + (size_t)(tn * 128) * 1024;

  f32x4 acc[4][4] = {};

  for (int k0 = 0; k0 < 1024; k0 += 64) {
    stage_tile(Ap + k0, smem, tid);
    stage_tile(Wp + k0, smem + 16384, tid);
    __syncthreads();
    bf16x8 af[4][2], bfr[4][2];
#pragma unroll
    for (int m = 0; m < 4; ++m) {
      const int ar = wm * 64 + m * 16 + lrow;
#pragma unroll
      for (int kk = 0; kk < 2; ++kk)
        af[m][kk] = *reinterpret_cast<const bf16x8*>(
            smem + ar * 128 + ((kk * 64 + lhi * 16) ^ xr));
    }
#pragma unroll
    for (int nn = 0; nn < 4; ++nn) {
      const int br = wn * 64 + nn * 16 + lrow;
#pragma unroll
      for (int kk = 0; kk < 2; ++kk)
        bfr[nn][kk] = *reinterpret_cast<const bf16x8*>(
            smem + 16384 + br * 128 + ((kk * 64 + lhi * 16) ^ xr));
    }
    __builtin_amdgcn_s_setprio(1);
#pragma unroll
    for (int kk = 0; kk < 2; ++kk)
#pragma unroll
      for (int m = 0; m < 4; ++m)
#pragma unroll
        for (int nn = 0; nn < 4; ++nn)
          acc[m][nn] = __builtin_amdgcn_mfma_f32_16x16x32_bf16(
              af[m][kk], bfr[nn][kk], acc[m][nn], 0, 0, 0);
    __builtin_amdgcn_s_setprio(0);
    __syncthreads();
  }

  // ---- epilogue: per-wave 8 KB LDS slice -> coalesced 16B stores
  char* epi = smem + wid * 8192;
  const int grow0 = row0 + wm * 64;

  if constexpr (MODE == 0) {
    const int sel = tn >> 3;
    const int cloc = (tn & 7) * 128 + wn * 64;
    const float* bias = sel == 0 ? b0 : sel == 1 ? b1 : b2;
    float bv4[4];
#pragma unroll
    for (int nn = 0; nn < 4; ++nn) bv4[nn] = bias[cloc + nn * 16 + lrow];

    if (sel != 2) {
      __hip_bfloat16* dst = sel == 0 ? (__hip_bfloat16*)O0 : (__hip_bfloat16*)O1;
#pragma unroll
      for (int mg = 0; mg < 4; ++mg) {
#pragma unroll
        for (int nn = 0; nn < 4; ++nn)
#pragma unroll
          for (int i = 0; i < 4; ++i) {
            float v = acc[mg][nn][i] + bv4[nn];
            if (sel == 0) v *= SC;
            ((__hip_bfloat16*)epi)[(lhi * 4 + i) * 72 + nn * 16 + lrow] =
                __float2bfloat16(v);
          }
#pragma unroll
        for (int ps = 0; ps < 2; ++ps) {
          const int r = ps * 8 + (lane >> 3);
          bf16x8 val = *reinterpret_cast<const bf16x8*>(epi + r * 144 + (lane & 7) * 16);
          const int grow = grow0 + mg * 16 + r;
          *reinterpret_cast<bf16x8*>(&dst[(size_t)grow * 1024 + cloc + (lane & 7) * 8]) = val;
        }
      }
    } else {
      __hip_bfloat16* dst = (__hip_bfloat16*)O2;
      const int h = cloc >> 6;
      const int bb = grow0 >> 11;
      const int t0 = grow0 & 2047;
      __hip_bfloat16* vb = dst + ((size_t)(bb * 16 + h) * 64) * 2048;
#pragma unroll
      for (int ng = 0; ng < 4; ++ng) {
#pragma unroll
        for (int m = 0; m < 4; ++m)
#pragma unroll
          for (int i = 0; i < 4; ++i) {
            const float v = acc[m][ng][i] + bv4[ng];
            ((__hip_bfloat16*)epi)[lrow * 72 + m * 16 + lhi * 4 + i] =
                __float2bfloat16(v);
          }
#pragma unroll
        for (int ps = 0; ps < 2; ++ps) {
          const int dr = ps * 8 + (lane >> 3);
          bf16x8 val = *reinterpret_cast<const bf16x8*>(epi + dr * 144 + (lane & 7) * 16);
          const int d = ng * 16 + dr;
          *reinterpret_cast<bf16x8*>(&vb[(size_t)d * 2048 + t0 + (lane & 7) * 8]) = val;
        }
      }
    }
  } else {
    float* dst = (float*)O0;
    const int cloc = tn * 128 + wn * 64;
    float bv4[4];
#pragma unroll
    for (int nn = 0; nn < 4; ++nn) bv4[nn] = b0[cloc + nn * 16 + lrow];
#pragma unroll
    for (int mg = 0; mg < 4; ++mg) {
#pragma unroll
      for (int nn = 0; nn < 4; ++nn)
#pragma unroll
        for (int i = 0; i < 4; ++i)
          ((float*)epi)[(lhi * 4 + i) * 68 + nn * 16 + lrow] =
              acc[mg][nn][i] + bv4[nn];
#pragma unroll
      for (int ps = 0; ps < 4; ++ps) {
        const int r = ps * 4 + (lane >> 4);
        float4 val = *reinterpret_cast<const float4*>(epi + r * 272 + (lane & 15) * 16);
        const int grow = grow0 + mg * 16 + r;
        *reinterpret_cast<float4*>(&dst[(size_t)grow * 1024 + cloc + (lane & 15) * 4]) = val;
      }
    }
  }
}

// ---------------- flash attention: paired complementary q-tiles ------------
// Block = 4 waves; each wave owns 32 q-rows of tile A (qtA = 15-pr, heavy)
// AND 32 q-rows of tile B (qtB = pr, light). qtA+qtB = 15 -> every block
// computes ~33 wave-steps (uniform) -> 512 blocks = 2/CU, zero makespan tail.
// Both co-resident blocks of a CU share bh (K/V L1/L2 reuse). K/V staged in
// shared double-buffered LDS (XOR-swizzle both sides); P buffer shared by
// both tiles (in-order DS per wave: B's writes execute after A's reads).
__device__ __forceinline__ void stage_kv(char* __restrict__ smem, int buf,
                                         const __hip_bfloat16* __restrict__ Kb,
                                         const __hip_bfloat16* __restrict__ Vb,
                                         int kv0, int tid) {
  const int w = tid >> 6, l = tid & 63;
  char* base = smem + buf * 16384;
#pragma unroll
  for (int s = 0; s < 2; ++s) {
    const int c = s * 256 + w * 64 + l;
    const int row = c >> 3;
    const int scb = ((c & 7) << 4) ^ ((row & 7) << 4);
    __builtin_amdgcn_global_load_lds(
        (const __attribute__((address_space(1))) void*)(Kb + (size_t)(kv0 + row) * 1024 + (scb >> 1)),
        (__attribute__((address_space(3))) void*)(base + s * 4096 + w * 1024), 16, 0, 0);
  }
#pragma unroll
  for (int s = 0; s < 2; ++s) {
    const int c = s * 256 + w * 64 + l;
    const int row = c >> 3;
    const int scb = ((c & 7) << 4) ^ ((row & 7) << 4);
    __builtin_amdgcn_global_load_lds(
        (const __attribute__((address_space(1))) void*)(Vb + (size_t)row * 2048 + kv0 + (scb >> 1)),
        (__attribute__((address_space(3))) void*)(base + 8192 + s * 4096 + w * 1024), 16, 0, 0);
  }
}

template <bool MASKED>
__device__ __forceinline__ void attn_step(
    int kv0, int q0w, int lrow, int lhi, const char* __restrict__ kvb,
    const bf16x8 qf[2][2], f32x4 o[2][4], float m[2], float l[2],
    __hip_bfloat16* __restrict__ P) {
  constexpr float TH = 8.0f;
  const int xr = (lrow & 7) << 4;
  f32x4 s[2][4] = {};
  __builtin_amdgcn_s_setprio(1);
#pragma unroll
  for (int g = 0; g < 4; ++g) {
    const char* rowp = kvb + (g * 16 + lrow) * 128;
#pragma unroll
    for (int kk = 0; kk < 2; ++kk) {
      bf16x8 kf = *reinterpret_cast<const bf16x8*>(rowp + ((kk * 64 + lhi * 16) ^ xr));
#pragma unroll
      for (int j = 0; j < 2; ++j)
        s[j][g] = __builtin_amdgcn_mfma_f32_16x16x32_bf16(kf, qf[j][kk], s[j][g], 0, 0, 0);
    }
  }
  __builtin_amdgcn_s_setprio(0);
  float mx[2];
#pragma unroll
  for (int j = 0; j < 2; ++j) {
    if (MASKED) {
#pragma unroll
      for (int g = 0; g < 4; ++g)
#pragma unroll
        for (int i = 0; i < 4; ++i) {
          const int k = kv0 + g * 16 + lhi * 4 + i;
          if (k > q0w + j * 16 + lrow) s[j][g][i] = -1e30f;
        }
    }
    float gm[4];
#pragma unroll
    for (int g = 0; g < 4; ++g)
      gm[g] = fmaxf(fmaxf(s[j][g][0], s[j][g][1]), fmaxf(s[j][g][2], s[j][g][3]));
    float t = fmaxf(fmaxf(gm[0], gm[1]), fmaxf(gm[2], gm[3]));
    t = fmaxf(t, __shfl_xor(t, 16));
    t = fmaxf(t, __shfl_xor(t, 32));
    mx[j] = t;
  }
  const int need = (mx[0] > m[0] + TH) || (mx[1] > m[1] + TH);
  if (__any(need)) {
#pragma unroll
    for (int j = 0; j < 2; ++j) {
      const float nm = fmaxf(m[j], mx[j]);
      const float al = EXP2F(m[j] - nm);
      m[j] = nm;
      l[j] *= al;
      float a4[4];
#pragma unroll
      for (int i = 0; i < 4; ++i) a4[i] = __shfl(al, 4 * lhi + i, 16);
#pragma unroll
      for (int f = 0; f < 4; ++f)
#pragma unroll
        for (int i = 0; i < 4; ++i) o[j][f][i] *= a4[i];
    }
  }
#pragma unroll
  for (int j = 0; j < 2; ++j) {
    float gs[4];
#pragma unroll
    for (int g = 0; g < 4; ++g) {
      bf16x4_s t4;
      float p0 = EXP2F(s[j][g][0] - m[j]);
      float p1 = EXP2F(s[j][g][1] - m[j]);
      float p2 = EXP2F(s[j][g][2] - m[j]);
      float p3 = EXP2F(s[j][g][3] - m[j]);
      t4.h[0] = __float2bfloat16(p0); t4.h[1] = __float2bfloat16(p1);
      t4.h[2] = __float2bfloat16(p2); t4.h[3] = __float2bfloat16(p3);
      gs[g] = (p0 + p1) + (p2 + p3);
      *reinterpret_cast<bf16x4_s*>(P + (j * 16 + lrow) * 72 + g * 16 + lhi * 4) = t4;
    }
    float sum = (gs[0] + gs[1]) + (gs[2] + gs[3]);
    sum += __shfl_xor(sum, 16);
    sum += __shfl_xor(sum, 32);
    l[j] += sum;
  }
  bf16x8 pf[2][2];
#pragma unroll
  for (int j = 0; j < 2; ++j)
#pragma unroll
    for (int n = 0; n < 2; ++n)
      pf[j][n] = *reinterpret_cast<const bf16x8*>(P + (j * 16 + lrow) * 72 + n * 32 + lhi * 8);
  __builtin_amdgcn_s_setprio(1);
#pragma unroll
  for (int n = 0; n < 2; ++n)
#pragma unroll
    for (int f = 0; f < 4; ++f) {
      bf16x8 vf = *reinterpret_cast<const bf16x8*>(
          kvb + 8192 + (f * 16 + lrow) * 128 + ((n * 64 + lhi * 16) ^ xr));
#pragma unroll
      for (int j = 0; j < 2; ++j)
        o[j][f] = __builtin_amdgcn_mfma_f32_16x16x32_bf16(pf[j][n], vf, o[j][f], 0, 0, 0);
    }
  __builtin_amdgcn_s_setprio(0);
}

__global__ __launch_bounds__(256, 2) void attn_fwd(
    const __hip_bfloat16* __restrict__ Q, const __hip_bfloat16* __restrict__ Km,
    const __hip_bfloat16* __restrict__ Vt, __hip_bfloat16* __restrict__ Y) {
  constexpr int T = 2048, C = 1024, D = 64;
  const int tid = threadIdx.x;
  const int wid = tid >> 6;
  const int lane = tid & 63;
  const int lrow = lane & 15;
  const int lhi = lane >> 4;
  // 512 blocks: xcd = n&7 owns bh group; pr = pair index.
  const int n = blockIdx.x;
  const int xcd = n & 7;
  const int w8 = n >> 3;                 // 0..63
  const int bh = xcd * 8 + (w8 & 7);
  const int pr = w8 >> 3;                // 0..7
  const int qtA = 15 - pr;               // heavy tile
  const int qtB = pr;                    // light tile
  const int b = bh >> 4, h = bh & 15;
  const int q0A = qtA * 128 + wid * 32;
  const int q0B = qtB * 128 + wid * 32;

  const __hip_bfloat16* Qb = Q + ((size_t)b * T) * C + h * D;
  const __hip_bfloat16* Kb = Km + ((size_t)b * T) * C + h * D;
  const __hip_bfloat16* Vb = Vt + (size_t)bh * D * T;

  __shared__ char smem[51200];
  __hip_bfloat16* P = (__hip_bfloat16*)(smem + 32768 + wid * 4608);

  bf16x8 qfA[2][2], qfB[2][2];
#pragma unroll
  for (int j = 0; j < 2; ++j)
#pragma unroll
    for (int kk = 0; kk < 2; ++kk) {
      qfA[j][kk] = *reinterpret_cast<const bf16x8*>(
          Qb + (size_t)(q0A + j * 16 + lrow) * C + kk * 32 + lhi * 8);
      qfB[j][kk] = *reinterpret_cast<const bf16x8*>(
          Qb + (size_t)(q0B + j * 16 + lrow) * C + kk * 32 + lhi * 8);
    }

  f32x4 oA[2][4] = {}, oB[2][4] = {};
  float mA[2] = {-1e30f, -1e30f}, lA[2] = {0.f, 0.f};
  float mB[2] = {-1e30f, -1e30f}, lB[2] = {0.f, 0.f};

  const int nt = 2 * qtA + 2;           // stream length (heavy tile)
  const int nsA = (q0A >> 6) + 1;
  const int nsB = (q0B >> 6) + 1;

  stage_kv(smem, 0, Kb, Vb, 0, tid);
  for (int t = 0; t < nt; ++t) {
    __syncthreads();
    if (t + 1 < nt) stage_kv(smem, (t + 1) & 1, Kb, Vb, (t + 1) * 64, tid);
    const char* kvb = smem + (t & 1) * 16384;
    if (t < nsA) {
      if (t == nsA - 1)
        attn_step<true>(t * 64, q0A, lrow, lhi, kvb, qfA, oA, mA, lA, P);
      else
        attn_step<false>(t * 64, q0A, lrow, lhi, kvb, qfA, oA, mA, lA, P);
    }
    if (t < nsB) {
      if (t == nsB - 1)
        attn_step<true>(t * 64, q0B, lrow, lhi, kvb, qfB, oB, mB, lB, P);
      else
        attn_step<false>(t * 64, q0B, lrow, lhi, kvb, qfB, oB, mB, lB, P);
    }
  }

  // ---- normalize + store (both tiles)
#pragma unroll
  for (int j = 0; j < 2; ++j) {
    float l4[4];
#pragma unroll
    for (int i = 0; i < 4; ++i) l4[i] = __shfl(lA[j], 4 * lhi + i, 16);
#pragma unroll
    for (int f = 0; f < 4; ++f)
#pragma unroll
      for (int i = 0; i < 4; ++i) {
        const int row = q0A + j * 16 + 4 * lhi + i;
        Y[((size_t)b * T + row) * C + h * D + f * 16 + lrow] =
            __float2bfloat16(oA[j][f][i] / l4[i]);
      }
  }
#pragma unroll
  for (int j = 0; j < 2; ++j) {
    float l4[4];
#pragma unroll
    for (int i = 0; i < 4; ++i) l4[i] = __shfl(lB[j], 4 * lhi + i, 16);
#pragma unroll
    for (int f = 0; f < 4; ++f)
#pragma unroll
      for (int i = 0; i < 4; ++i) {
        const int row = q0B + j * 16 + 4 * lhi + i;
        Y[((size_t)b * T + row) * C + h * D + f * 16 + lrow] =
            __float2bfloat16(oB[j][f][i] / l4[i]);
      }
  }
}

// ---------------- host launch ----------------------------------------------
extern "C" void kernel_launch(void* const* d_in, const int* in_sizes, int n_in,
                              void* d_out, int out_size, void* d_ws,
                              size_t ws_size, hipStream_t stream) {
  const float* x = (const float*)d_in[0];
  const float* Wq = (const float*)d_in[1];
  const float* bq = (const float*)d_in[2];
  const float* Wk = (const float*)d_in[3];
  const float* bk = (const float*)d_in[4];
  const float* Wv = (const float*)d_in[5];
  const float* bv = (const float*)d_in[6];
  const float* Wp = (const float*)d_in[7];
  const float* bp = (const float*)d_in[8];
  float* out = (float*)d_out;

  __hip_bfloat16* ws = (__hip_bfloat16*)d_ws;
  __hip_bfloat16* xb = ws;                   // 8388608
  __hip_bfloat16* wqb = xb + 8388608;        // 4 x 1048576, contiguous
  __hip_bfloat16* wpb = wqb + 3 * 1048576;
  __hip_bfloat16* Qs = wqb + 4 * 1048576;    // 8388608
  __hip_bfloat16* Ks = Qs + 8388608;
  __hip_bfloat16* Vts = Ks + 8388608;        // V^T: [B*H*64][2048]
  __hip_bfloat16* Ys = Vts + 8388608;        // attn out [B*T][C]

  cvt_kernel<<<4096, 256, 0, stream>>>(x, xb, 1048576);
  cvt4_kernel<<<2048, 256, 0, stream>>>(Wq, Wk, Wv, Wp, wqb);

  gemm128<0><<<dim3(1536), 256, 0, stream>>>(xb, wqb, bq, bk, bv, Qs, Ks, Vts);

  attn_fwd<<<dim3(512), 256, 0, stream>>>(Qs, Ks, Vts, Ys);

  gemm128<1><<<dim3(512), 256, 0, stream>>>(Ys, wpb, bp, nullptr, nullptr, out,
                                            nullptr, nullptr);
}